// Round 10
// baseline (304.332 us; speedup 1.0000x reference)
//
#include <hip/hip_runtime.h>
#include <math.h>

#define BATCH 8192
#define NROW 512
#define NCOL 512
#define MNODE 256
#define PL 524288  // ushorts per bf16 plane (512*1024)

typedef __attribute__((ext_vector_type(8))) short bf16x8;
typedef __attribute__((ext_vector_type(4))) short s16x4;
typedef __attribute__((ext_vector_type(4))) float f32x4;

// Split fp32 into truncated-bf16 hi + bf16(lo residual). a ~= hi + lo.
__device__ __forceinline__ short2 split1(float x) {
  unsigned u = __float_as_uint(x);
  short h = (short)(u >> 16);
  float r = x - __uint_as_float(u & 0xffff0000u);
  short l = (short)(__float_as_uint(r) >> 16);
  return make_short2(h, l);
}

// ---------------------------------------------------------------------------
// Fused per-node 2x2 complex matrix (verified).
// ---------------------------------------------------------------------------
__global__ __launch_bounds__(256) void precomp_kernel(
    const float* __restrict__ thetas, const float* __restrict__ phis,
    const float* __restrict__ bse, const float* __restrict__ lse,
    float4* __restrict__ pp) {
  int n = blockIdx.x * 256 + threadIdx.x;
  float th = thetas[n], ph = phis[n];
  float e0 = bse[2 * n + 0], e1 = bse[2 * n + 1];
  float l0 = lse[2 * n + 0], l1 = lse[2 * n + 1];
  const float K = 0.16609640474436813f;  // log2(10)/20
  float ins0 = exp2f(l0 * K), ins1 = exp2f(l1 * K);
  const float PI4 = 0.7853981633974483f;
  float s0, c0, s1, c1, sp, cp, st, ct;
  sincosf(PI4 + e0, &s0, &c0);
  sincosf(PI4 + e1, &s1, &c1);
  sincosf(ph, &sp, &cp);
  sincosf(th, &st, &ct);
  float AL = ins0 * s0, C1L = c0, C2L = ins0 * c0, SL = s0;
  float AR = ins1 * s1, C1R = c1, C2R = ins1 * c1, SR = s1;
  float a11r = AL * cp,   a11i = AL * sp;
  float a12r = 0.f,       a12i = C1L;
  float a21r = -C2L * sp, a21i = C2L * cp;
  float a22r = SL,        a22i = 0.f;
  float b11r = a11r * ct - a11i * st, b11i = a11r * st + a11i * ct;
  float b12r = a12r * ct - a12i * st, b12i = a12r * st + a12i * ct;
  float n11r = AR * b11r - C1R * a21i;
  float n11i = AR * b11i + C1R * a21r;
  float n12r = AR * b12r - C1R * a22i;
  float n12i = AR * b12i + C1R * a22r;
  float n21r = -C2R * b11i + SR * a21r;
  float n21i =  C2R * b11r + SR * a21i;
  float n22r = -C2R * b12i + SR * a22r;
  float n22i =  C2R * b12r + SR * a22i;
  pp[2 * n + 0] = make_float4(n11r, n11i, n12r, n12i);
  pp[2 * n + 1] = make_float4(n21r, n21i, n22r, n22i);
}

__device__ __forceinline__ void proc_pair(float& vtr, float& vti, float& vbr, float& vbi,
                                          const float4 q0, const float4 q1) {
  float tr = q0.x * vtr - q0.y * vti + q0.z * vbr - q0.w * vbi;
  float ti = q0.x * vti + q0.y * vtr + q0.z * vbi + q0.w * vbr;
  float br = q1.x * vtr - q1.y * vti + q1.z * vbr - q1.w * vbi;
  float bi = q1.x * vti + q1.y * vtr + q1.z * vbi + q1.w * vbr;
  vtr = tr; vti = ti; vbr = br; vbi = bi;
}

__device__ __forceinline__ int swz(int b) { return b ^ ((b >> 3) & 7); }

// ---------------------------------------------------------------------------
// BAND-COMPACT COMPOSE (verified round 5) + dual-format epilogue (round 6)
// + load predication (verified round 8).
// ---------------------------------------------------------------------------
__global__ __launch_bounds__(256) void compose_band(
    const float* __restrict__ gammas, const float4* __restrict__ pp,
    float* __restrict__ Tsegs, int P) {
  __shared__ float ep[5120];  // [row(0..511)=re, 512+row=im][5]

  const int tid  = threadIdx.x;
  const int lane = tid & 63;
  const int w    = tid >> 6;
  const int seg  = blockIdx.x >> 7;
  const int g    = blockIdx.x & 127;
  const int col  = g * 4 + w;

  const float4* ps = pp + (size_t)seg * P * 1024;
  float* T = Tsegs + (size_t)seg * (1024 * NROW);

  const int colA = (col - 63) & ~1;        // even, slots [colA, colA+127]
  const int E    = colA + 2 * lane;        // my even row; rows E, E+1
  const int je   = E >> 1;
  const int jeC  = je < 0 ? 0 : (je > 255 ? 255 : je);

  const bool vE  = (E >= 0) && (E <= 510);
  const bool vOT = (E >= 0) && (E <= 508);
  const bool vOB = (E >= 2) && (E <= 510);

  float ar = 0.f, ai = 0.f, br = 0.f, bi = 0.f;
  {
    float vr0 = 1.f, vi0 = 0.f;
    if (seg == 0) {
      float sg, cg;
      sincosf(gammas[col], &sg, &cg);
      vr0 = cg; vi0 = sg;
    }
    if (E == col)     { ar = vr0; ai = vi0; }
    if (E + 1 == col) { br = vr0; bi = vi0; }
  }

  const float4* pe = ps + 2 * jeC;
  const float4* po = ps + 512 + 2 * jeC;

  float sar = 0.f, sai = 0.f, sbr = 0.f, sbi = 0.f;

  for (int p = 0; p < P; ++p) {
    // band predicate: rows (E,E+1) intersect [col-2p-2, col+2p+2], margin 2
    const bool actp = (E >= col - 2 * p - 5) && (E <= col + 2 * p + 4);

    float4 o0, o1;
    if (actp) {
      float4 q0 = pe[0];
      float4 q1 = pe[1];
      o0 = po[0];
      o1 = po[-1];

      // even pair (E, E+1)
      float tr = q0.x * ar - q0.y * ai + q0.z * br - q0.w * bi;
      float ti = q0.x * ai + q0.y * ar + q0.z * bi + q0.w * br;
      float ur = q1.x * ar - q1.y * ai + q1.z * br - q1.w * bi;
      float ui = q1.x * ai + q1.y * ar + q1.z * bi + q1.w * br;
      if (vE) { ar = tr; ai = ti; br = ur; bi = ui; }
    }
    pe += 1024; po += 1024;

    if (p == P - 1) { sar = ar; sai = ai; sbr = br; sbi = bi; }

    // neighbor values post-even (all lanes execute; inactive lanes hold 0)
    float anr = __shfl_down(ar, 1, 64);
    float ani = __shfl_down(ai, 1, 64);
    float bpr = __shfl_up(br, 1, 64);
    float bpi = __shfl_up(bi, 1, 64);
    if (lane == 63) { anr = 0.f; ani = 0.f; }
    if (lane == 0)  { bpr = 0.f; bpi = 0.f; }

    if (actp) {
      float tr = o0.x * br - o0.y * bi + o0.z * anr - o0.w * ani;
      float ti = o0.x * bi + o0.y * br + o0.z * ani + o0.w * anr;
      float ur = o1.x * bpr - o1.y * bpi + o1.z * ar - o1.w * ai;
      float ui = o1.x * bpi + o1.y * bpr + o1.z * ai + o1.w * ar;
      if (vOT) { br = tr; bi = ti; }
      if (vOB) { ar = ur; ai = ui; }
    }
  }

  // spill row (exactly one, final odd phase, closed form)
  int sprow = -1;
  float spr = 0.f, spi = 0.f;
  if ((col & 1) == 0) {
    if (colA + 128 <= 511) {
      sprow = colA + 128;
      float4 w1 = ps[(size_t)(P - 1) * 1024 + 512 + 2 * (colA / 2 + 63) + 1];
      float vtr = __shfl(sbr, 63, 64);
      float vti = __shfl(sbi, 63, 64);
      spr = w1.x * vtr - w1.y * vti;
      spi = w1.x * vti + w1.y * vtr;
    }
  } else {
    if (colA - 1 >= 0) {
      sprow = colA - 1;
      float4 w0 = ps[(size_t)(P - 1) * 1024 + 512 + 2 * (colA / 2 - 1)];
      float vbr = __shfl(sar, 0, 64);
      float vbi = __shfl(sai, 0, 64);
      spr = w0.z * vbr - w0.w * vbi;
      spi = w0.z * vbi + w0.w * vbr;
    }
  }

  // deposit into zeroed transpose buffer
  for (int i = tid; i < 5120; i += 256) ep[i] = 0.f;
  __syncthreads();
  if (E >= 0 && E <= 510) {
    ep[E * 5 + w]         = ar;
    ep[(512 + E) * 5 + w] = ai;
    ep[(E + 1) * 5 + w]   = br;
    ep[(513 + E) * 5 + w] = bi;
  }
  if (lane == 0 && sprow >= 0) {
    ep[sprow * 5 + w]         = spr;
    ep[(512 + sprow) * 5 + w] = spi;
  }
  __syncthreads();

  if (seg & 1) {
    // A-side: normal float [1024][512]
#pragma unroll
    for (int k = 0; k < 4; ++k) {
      const int i = k * 256 + tid;
      *(float4*)(T + (size_t)i * NROW + g * 4) =
          make_float4(ep[i * 5 + 0], ep[i * 5 + 1], ep[i * 5 + 2], ep[i * 5 + 3]);
    }
  } else {
    // B-side: transposed bf16-split planes [n][k]
    unsigned short* Thi = (unsigned short*)T;
    unsigned short* Tlo = Thi + PL;
    const int c  = tid & 3;           // column within block
    const int k0 = (tid >> 2) * 16;   // 16 k-entries per thread
    const int colg = g * 4 + c;
    short hh[16], ll[16];
#pragma unroll
    for (int j = 0; j < 16; ++j) {
      short2 s = split1(ep[(k0 + j) * 5 + c]);
      hh[j] = s.x; ll[j] = s.y;
    }
    *(bf16x8*)&Thi[(size_t)colg * 1024 + k0]     = *(bf16x8*)&hh[0];
    *(bf16x8*)&Thi[(size_t)colg * 1024 + k0 + 8] = *(bf16x8*)&hh[8];
    *(bf16x8*)&Tlo[(size_t)colg * 1024 + k0]     = *(bf16x8*)&ll[0];
    *(bf16x8*)&Tlo[(size_t)colg * 1024 + k0 + 8] = *(bf16x8*)&ll[8];
  }
}

// ---------------------------------------------------------------------------
// MERGE v2 (REVERTED to verified round-6/7 staged version): A float normal
// (LDS-staged, coalesced, sign-twiddled quadrants), B bf16^T planes,
// dual-format output, band-limited K window. Round-9's barrier-free variant
// regressed (~10-20 us: 64-line/instr A-gather at 1 wave/SIMD) — reverted.
// ---------------------------------------------------------------------------
__global__ __launch_bounds__(256) void merge_t(
    const float* __restrict__ Ab, long sA,
    const unsigned short* __restrict__ Bb, long sB,
    unsigned short* __restrict__ Cub, long sCu,
    float* __restrict__ Cfb, long sCf,
    int HA, int HB, int force_f) {
  const int z = blockIdx.z;
  const float* A = Ab + (long)z * sA;
  const unsigned short* B = Bb + (long)z * sB;
  const bool fout = force_f || (z & 1);
  unsigned short* Cu = Cub + (long)(z >> 1) * sCu;
  float*          Cf = Cfb + (long)(z >> 1) * sCf;

  __shared__ short sAh[64 * 40], sAl[64 * 40];  // [m][k] bf16, stride 40

  const int tid = threadIdx.x;
  const int lane = tid & 63;
  const int w = tid >> 6;
  const int bm = blockIdx.y * 64;
  const int bn = blockIdx.x * 64;
  const int wm = (w & 1) * 32;
  const int wn = (w >> 1) * 32;
  const int q = lane >> 4;
  const int l15 = lane & 15;

  const int sm = tid >> 2;
  const int sk = (tid & 3) * 8;

  // band-limited K window (block-uniform)
  const int rmin = (blockIdx.y & 7) * 64;
  int klo = rmin - HA;
  {
    int t = bn - HB;
    if (t > klo) klo = t;
    if (klo < 0) klo = 0;
  }
  int khi = rmin + 63 + HA;
  {
    int t = bn + 63 + HB;
    if (t < khi) khi = t;
    if (khi > 511) khi = 511;
  }
  klo &= ~31;

  f32x4 acc[2][2];
#pragma unroll
  for (int i = 0; i < 2; ++i)
#pragma unroll
    for (int j = 0; j < 2; ++j) acc[i][j] = (f32x4){0.f, 0.f, 0.f, 0.f};

  if (klo <= khi) {
#pragma unroll 1
    for (int h = 0; h < 2; ++h) {
#pragma unroll 1
      for (int k0 = klo; k0 <= khi; k0 += 32) {
        const int gkb = h * 512 + k0;
        // stage A' tile [64m x 32k] with quadrant select + sign
        {
          const int gm = bm + sm;
          const int gk = gkb + sk;
          const int r = gm & 511;
          const bool top = gm < 512;
          const bool left = gk < 512;
          const int col = gk & 511;
          const float* src = (top == left) ? (A + (size_t)r * 512)
                                           : (A + (size_t)(512 + r) * 512);
          const float sgn = (top && !left) ? -1.f : 1.f;
          float4 v0 = *(const float4*)(src + col);
          float4 v1 = *(const float4*)(src + col + 4);
          float vv[8] = {v0.x, v0.y, v0.z, v0.w, v1.x, v1.y, v1.z, v1.w};
          short hh[8], ll[8];
#pragma unroll
          for (int i = 0; i < 8; ++i) {
            short2 s = split1(sgn * vv[i]);
            hh[i] = s.x; ll[i] = s.y;
          }
          __syncthreads();
          *(bf16x8*)&sAh[sm * 40 + sk] = *(bf16x8*)hh;
          *(bf16x8*)&sAl[sm * 40 + sk] = *(bf16x8*)ll;
          __syncthreads();
        }

        // B fragments: 2 b128 loads each (pre-split planes)
        bf16x8 bh[2], bl[2];
#pragma unroll
        for (int nt = 0; nt < 2; ++nt) {
          const unsigned short* bp =
              B + (size_t)(bn + wn + nt * 16 + l15) * 1024 + gkb + q * 8;
          bh[nt] = *(const bf16x8*)bp;
          bl[nt] = *(const bf16x8*)(bp + PL);
        }

        // A fragments
        bf16x8 ah[2], al[2];
#pragma unroll
        for (int mt = 0; mt < 2; ++mt) {
          const int m = wm + mt * 16 + l15;
          ah[mt] = *(const bf16x8*)&sAh[m * 40 + q * 8];
          al[mt] = *(const bf16x8*)&sAl[m * 40 + q * 8];
        }

#pragma unroll
        for (int mt = 0; mt < 2; ++mt)
#pragma unroll
          for (int nt = 0; nt < 2; ++nt) {
            acc[mt][nt] = __builtin_amdgcn_mfma_f32_16x16x32_bf16(ah[mt], bh[nt], acc[mt][nt], 0, 0, 0);
            acc[mt][nt] = __builtin_amdgcn_mfma_f32_16x16x32_bf16(ah[mt], bl[nt], acc[mt][nt], 0, 0, 0);
            acc[mt][nt] = __builtin_amdgcn_mfma_f32_16x16x32_bf16(al[mt], bh[nt], acc[mt][nt], 0, 0, 0);
          }
      }
    }
  }

  if (fout) {
#pragma unroll
    for (int mt = 0; mt < 2; ++mt)
#pragma unroll
      for (int nt = 0; nt < 2; ++nt)
#pragma unroll
        for (int r = 0; r < 4; ++r) {
          const int gm = bm + wm + mt * 16 + q * 4 + r;
          const int gn = bn + wn + nt * 16 + l15;
          Cf[(size_t)gm * 512 + gn] = acc[mt][nt][r];
        }
  } else {
    unsigned short* Chi = Cu;
    unsigned short* Clo = Cu + PL;
#pragma unroll
    for (int mt = 0; mt < 2; ++mt)
#pragma unroll
      for (int nt = 0; nt < 2; ++nt) {
        short hh[4], ll[4];
#pragma unroll
        for (int r = 0; r < 4; ++r) {
          short2 s = split1(acc[mt][nt][r]);
          hh[r] = s.x; ll[r] = s.y;
        }
        const int gm0 = bm + wm + mt * 16 + q * 4;
        const int gn  = bn + wn + nt * 16 + l15;
        *(s16x4*)&Chi[(size_t)gn * 1024 + gm0] = *(s16x4*)hh;
        *(s16x4*)&Clo[(size_t)gn * 1024 + gm0] = *(s16x4*)ll;
      }
  }
}

// ---------------------------------------------------------------------------
// LEGACY COMPOSE + MERGE (verified; ws < 24 MB fallback).
// ---------------------------------------------------------------------------
__global__ __launch_bounds__(256) void compose_kernel(
    const float* __restrict__ gammas, const float4* __restrict__ pp,
    float* __restrict__ Tsegs, int pairs_per_seg) {
  __shared__ float4 buf[2][1024];
  float* epf = (float*)buf;

  const int tid  = threadIdx.x;
  const int lane = tid & 63;
  const int w    = tid >> 6;
  const int seg  = blockIdx.x >> 7;
  const int g    = blockIdx.x & 127;
  const int col  = g * 4 + w;
  const int colmin = g * 4;

  const float4* ps = pp + (size_t)seg * pairs_per_seg * 1024;
  float* T = Tsegs + (size_t)seg * (1024 * NROW);

  float vr[8], vi[8];
#pragma unroll
  for (int r = 0; r < 8; ++r) {
    const int row = lane * 8 + r;
    vr[r] = 0.f; vi[r] = 0.f;
    if (row == col) {
      if (seg == 0) {
        float sg, cg;
        sincosf(gammas[row], &sg, &cg);
        vr[r] = cg; vi[r] = sg;
      } else {
        vr[r] = 1.f;
      }
    }
  }

  {
    const int sw = swz(tid);
#pragma unroll
    for (int k = 0; k < 4; ++k)
      buf[0][256 * k + sw] = ps[256 * k + tid];
  }
  __syncthreads();

  const int Lc = col >> 3;

#pragma unroll 1
  for (int p = 0; p < pairs_per_seg; ++p) {
    const int b = p & 1;

    const int HA = (p >> 2) + 3;
    const bool act  = (lane >= Lc - HA)     && (lane <= Lc + HA);
    const bool wide = (lane >= Lc - HA - 1) && (lane <= Lc + HA + 1);

    float4 f0, f1, f2, f3;
    bool st0 = false, st1 = false;
    if (p < pairs_per_seg - 1) {
      const int slo = colmin - 2 * p - 50;
      const int shi = colmin + 2 * p + 53;
      st0 = (tid + 1 >= slo) && (tid <= shi);
      st1 = (tid + 257 >= slo) && (tid + 256 <= shi);
      const float4* src = ps + (size_t)(p + 1) * 1024;
      if (st0) { f0 = src[tid];       f2 = src[512 + tid]; }
      if (st1) { f1 = src[256 + tid]; f3 = src[768 + tid]; }
    }

    float4 pe[8], po[7], pu1;
    if (act) {
      const int base = 8 * lane;
      const int l7 = lane & 7;
#pragma unroll
      for (int j = 0; j < 8; ++j) pe[j] = buf[b][base + (j ^ l7)];
#pragma unroll
      for (int j = 0; j < 7; ++j) po[j] = buf[b][512 + base + (j ^ l7)];
      const int lm = (lane == 0) ? 0 : lane - 1;
      pu1 = buf[b][512 + 8 * lm + (7 ^ (lm & 7))];

#pragma unroll
      for (int k = 0; k < 4; ++k)
        proc_pair(vr[2 * k], vi[2 * k], vr[2 * k + 1], vi[2 * k + 1],
                  pe[2 * k], pe[2 * k + 1]);

#pragma unroll
      for (int k = 0; k < 3; ++k)
        proc_pair(vr[2 * k + 1], vi[2 * k + 1], vr[2 * k + 2], vi[2 * k + 2],
                  po[2 * k], po[2 * k + 1]);
    }

    float br = 0.f, bi = 0.f, tu = 0.f, tv = 0.f;
    if (wide) {
      br = __shfl_down(vr[0], 1, 64);
      bi = __shfl_down(vi[0], 1, 64);
      tu = __shfl_up(vr[7], 1, 64);
      tv = __shfl_up(vi[7], 1, 64);
    }
    if (act) {
      float nAr = po[6].x * vr[7] - po[6].y * vi[7] + po[6].z * br - po[6].w * bi;
      float nAi = po[6].x * vi[7] + po[6].y * vr[7] + po[6].z * bi + po[6].w * br;
      float nBr = pu1.x * tu - pu1.y * tv + pu1.z * vr[0] - pu1.w * vi[0];
      float nBi = pu1.x * tv + pu1.y * tu + pu1.z * vi[0] + pu1.w * vr[0];
      if (lane < 63) { vr[7] = nAr; vi[7] = nAi; }
      if (lane > 0)  { vr[0] = nBr; vi[0] = nBi; }
    }

    if (p < pairs_per_seg - 1) {
      const int sw = swz(tid);
      if (st0) { buf[1 - b][sw] = f0;       buf[1 - b][512 + sw] = f2; }
      if (st1) { buf[1 - b][256 + sw] = f1; buf[1 - b][768 + sw] = f3; }
    }
    __syncthreads();
  }

#pragma unroll
  for (int r = 0; r < 8; ++r) {
    epf[(lane * 8 + r) * 5 + w] = vr[r];
    epf[(512 + lane * 8 + r) * 5 + w] = vi[r];
  }
  __syncthreads();
#pragma unroll
  for (int k = 0; k < 4; ++k) {
    const int i = k * 256 + tid;
    *(float4*)(T + (size_t)i * NROW + g * 4) =
        make_float4(epf[i * 5 + 0], epf[i * 5 + 1], epf[i * 5 + 2], epf[i * 5 + 3]);
  }
}

__global__ __launch_bounds__(256) void merge_g(
    const float* __restrict__ Ab, const float* __restrict__ Bb,
    float* __restrict__ Cb, long sA, long sB, long sC, int HA, int HB) {
  const float* A = Ab + (long)blockIdx.z * sA;
  const float* B = Bb + (long)blockIdx.z * sB;
  float*       C = Cb + (long)blockIdx.z * sC;

  __shared__ short sAh[64 * 40], sAl[64 * 40];

  const int tid = threadIdx.x;
  const int lane = tid & 63;
  const int w = tid >> 6;
  const int bm = blockIdx.y * 64;
  const int bn = blockIdx.x * 64;
  const int wm = (w & 1) * 32;
  const int wn = (w >> 1) * 32;
  const int q = lane >> 4;
  const int l15 = lane & 15;

  const int sm = tid >> 2;
  const int sk = (tid & 3) * 8;

  const int rmin = (blockIdx.y & 7) * 64;
  int klo = rmin - HA;
  {
    int t = bn - HB;
    if (t > klo) klo = t;
    if (klo < 0) klo = 0;
  }
  int khi = rmin + 63 + HA;
  {
    int t = bn + 63 + HB;
    if (t < khi) khi = t;
    if (khi > 511) khi = 511;
  }
  klo &= ~31;

  f32x4 acc[2][2];
#pragma unroll
  for (int i = 0; i < 2; ++i)
#pragma unroll
    for (int j = 0; j < 2; ++j) acc[i][j] = (f32x4){0.f, 0.f, 0.f, 0.f};

  if (klo <= khi) {
#pragma unroll 1
    for (int h = 0; h < 2; ++h) {
#pragma unroll 1
      for (int k0 = klo; k0 <= khi; k0 += 32) {
        const int gkb = h * 512 + k0;
        {
          const int gm = bm + sm;
          const int gk = gkb + sk;
          const int r = gm & 511;
          const bool top = gm < 512;
          const bool left = gk < 512;
          const int col = gk & 511;
          const float* src = (top == left) ? (A + (size_t)r * 512)
                                           : (A + (size_t)(512 + r) * 512);
          const float sgn = (top && !left) ? -1.f : 1.f;
          float4 v0 = *(const float4*)(src + col);
          float4 v1 = *(const float4*)(src + col + 4);
          float vv[8] = {v0.x, v0.y, v0.z, v0.w, v1.x, v1.y, v1.z, v1.w};
          short hh[8], ll[8];
#pragma unroll
          for (int i = 0; i < 8; ++i) {
            short2 s = split1(sgn * vv[i]);
            hh[i] = s.x; ll[i] = s.y;
          }
          __syncthreads();
          *(bf16x8*)&sAh[sm * 40 + sk] = *(bf16x8*)hh;
          *(bf16x8*)&sAl[sm * 40 + sk] = *(bf16x8*)ll;
          __syncthreads();
        }

        bf16x8 bh[2], bl[2];
#pragma unroll
        for (int nt = 0; nt < 2; ++nt) {
          const float* bp = B + (size_t)(gkb + q * 8) * 512 + bn + wn + nt * 16 + l15;
          short hh[8], ll[8];
#pragma unroll
          for (int j = 0; j < 8; ++j) {
            short2 s = split1(bp[(size_t)j * 512]);
            hh[j] = s.x; ll[j] = s.y;
          }
          bh[nt] = *(bf16x8*)hh;
          bl[nt] = *(bf16x8*)ll;
        }

        bf16x8 ah[2], al[2];
#pragma unroll
        for (int mt = 0; mt < 2; ++mt) {
          const int m = wm + mt * 16 + l15;
          ah[mt] = *(const bf16x8*)&sAh[m * 40 + q * 8];
          al[mt] = *(const bf16x8*)&sAl[m * 40 + q * 8];
        }

#pragma unroll
        for (int mt = 0; mt < 2; ++mt)
#pragma unroll
          for (int nt = 0; nt < 2; ++nt) {
            acc[mt][nt] = __builtin_amdgcn_mfma_f32_16x16x32_bf16(ah[mt], bh[nt], acc[mt][nt], 0, 0, 0);
            acc[mt][nt] = __builtin_amdgcn_mfma_f32_16x16x32_bf16(ah[mt], bl[nt], acc[mt][nt], 0, 0, 0);
            acc[mt][nt] = __builtin_amdgcn_mfma_f32_16x16x32_bf16(al[mt], bh[nt], acc[mt][nt], 0, 0, 0);
          }
      }
    }
  }

#pragma unroll
  for (int mt = 0; mt < 2; ++mt)
#pragma unroll
    for (int nt = 0; nt < 2; ++nt)
#pragma unroll
      for (int r = 0; r < 4; ++r) {
        const int gm = bm + wm + mt * 16 + q * 4 + r;
        const int gn = bn + wn + nt * 16 + l15;
        C[(size_t)gm * 512 + gn] = acc[mt][nt][r];
      }
}

// ---------------------------------------------------------------------------
// XPREP: split x[512][8192] into bf16 hi/lo in MFMA-fragment order.
// ---------------------------------------------------------------------------
__global__ __launch_bounds__(256) void xprep_kernel(
    const float* __restrict__ x, short* __restrict__ xp) {
  const int t = blockIdx.x * 256 + threadIdx.x;
  const int n = t & 8191;
  const int g = t >> 13;
  const float* src = x + (size_t)g * 8 * BATCH + n;
  short h[8], l[8];
#pragma unroll
  for (int j = 0; j < 8; ++j) {
    short2 s = split1(src[(size_t)j * BATCH]);
    h[j] = s.x; l[j] = s.y;
  }
  short* dst = xp + (size_t)t * 16;
  *(bf16x8*)dst = *(bf16x8*)h;
  *(bf16x8*)(dst + 8) = *(bf16x8*)l;
}

// ---------------------------------------------------------------------------
// APPLY v4 (verified round 7): BM=128, BN=128, packed-B fragment loads.
// ---------------------------------------------------------------------------
__global__ __launch_bounds__(256) void gemm_mfma_packed(
    const float* __restrict__ A, const short* __restrict__ xp,
    float* __restrict__ C) {
  __shared__ short sAh[128 * 40], sAl[128 * 40];

  const int tid = threadIdx.x;
  const int lane = tid & 63;
  const int w = tid >> 6;
  const int bm = blockIdx.y * 128;
  const int bn = blockIdx.x * 128;
  const int wm = (w & 1) * 64;
  const int wn = (w >> 1) * 64;
  const int q = lane >> 4;
  const int l15 = lane & 15;

  const int sm = tid >> 1;          // 0..127 staged row
  const int sk = (tid & 1) * 16;    // 0 or 16
  const float* Ap = A + (size_t)(bm + sm) * 512 + sk;

  f32x4 acc[4][4];
#pragma unroll
  for (int i = 0; i < 4; ++i)
#pragma unroll
    for (int j = 0; j < 4; ++j) acc[i][j] = (f32x4){0.f, 0.f, 0.f, 0.f};

  // prefetch first A slab (16 floats/thread)
  float4 pa[4];
#pragma unroll
  for (int i = 0; i < 4; ++i) pa[i] = *(const float4*)(Ap + i * 4);

#pragma unroll 1
  for (int k0 = 0; k0 < 512; k0 += 32) {
    // stage A slab
    {
      short h[16], l[16];
#pragma unroll
      for (int i = 0; i < 16; ++i) {
        short2 s = split1(((const float*)pa)[i]);
        h[i] = s.x; l[i] = s.y;
      }
      __syncthreads();
      *(bf16x8*)&sAh[sm * 40 + sk]     = *(bf16x8*)&h[0];
      *(bf16x8*)&sAh[sm * 40 + sk + 8] = *(bf16x8*)&h[8];
      *(bf16x8*)&sAl[sm * 40 + sk]     = *(bf16x8*)&l[0];
      *(bf16x8*)&sAl[sm * 40 + sk + 8] = *(bf16x8*)&l[8];
      __syncthreads();
    }

    // prefetch next A slab
    if (k0 + 32 < 512) {
#pragma unroll
      for (int i = 0; i < 4; ++i) pa[i] = *(const float4*)(Ap + k0 + 32 + i * 4);
    }

    // B fragments: packed coalesced loads
    const int kt = k0 >> 5;
    bf16x8 bh[4], bl[4];
#pragma unroll
    for (int nt = 0; nt < 4; ++nt) {
      const short* bp = xp + (((size_t)(kt * 4 + q)) * BATCH +
                              (bn + wn + nt * 16 + l15)) * 16;
      bh[nt] = *(const bf16x8*)bp;
      bl[nt] = *(const bf16x8*)(bp + 8);
    }

    // A fragments + MFMA (per-mt frag load to bound registers)
#pragma unroll
    for (int mt = 0; mt < 4; ++mt) {
      const int m = wm + mt * 16 + l15;
      bf16x8 ah = *(const bf16x8*)&sAh[m * 40 + q * 8];
      bf16x8 al = *(const bf16x8*)&sAl[m * 40 + q * 8];
#pragma unroll
      for (int nt = 0; nt < 4; ++nt) {
        acc[mt][nt] = __builtin_amdgcn_mfma_f32_16x16x32_bf16(ah, bh[nt], acc[mt][nt], 0, 0, 0);
        acc[mt][nt] = __builtin_amdgcn_mfma_f32_16x16x32_bf16(ah, bl[nt], acc[mt][nt], 0, 0, 0);
        acc[mt][nt] = __builtin_amdgcn_mfma_f32_16x16x32_bf16(al, bh[nt], acc[mt][nt], 0, 0, 0);
      }
    }
  }

  // epilogue: D[row=q*4+r][col=l15] per 16x16 tile
#pragma unroll
  for (int mt = 0; mt < 4; ++mt)
#pragma unroll
    for (int nt = 0; nt < 4; ++nt)
#pragma unroll
      for (int r = 0; r < 4; ++r) {
        const int gm = bm + wm + mt * 16 + q * 4 + r;
        const int gn = bn + wn + nt * 16 + l15;
        C[(size_t)gm * BATCH + gn] = acc[mt][nt][r];
      }
}

// ---------------------------------------------------------------------------
// APPLY v1 (legacy fallback, verified).
// ---------------------------------------------------------------------------
__global__ __launch_bounds__(256) void gemm_mfma(
    const float* __restrict__ A, const float* __restrict__ B,
    float* __restrict__ C) {
  __shared__ short sAh[128 * 40], sAl[128 * 40];

  const int tid = threadIdx.x;
  const int lane = tid & 63;
  const int w = tid >> 6;
  const int bm = blockIdx.y * 128;
  const int bn = blockIdx.x * 128;
  const int wm = (w & 1) * 64;
  const int wn = (w >> 1) * 64;
  const int q = lane >> 4;
  const int l15 = lane & 15;

  const int sm = tid >> 1;
  const int sk = (tid & 1) * 16;
  const float* Ap = A + (size_t)(bm + sm) * 512 + sk;

  f32x4 acc[4][4];
#pragma unroll
  for (int i = 0; i < 4; ++i)
#pragma unroll
    for (int j = 0; j < 4; ++j) acc[i][j] = (f32x4){0.f, 0.f, 0.f, 0.f};

  float4 pa[4];
#pragma unroll
  for (int i = 0; i < 4; ++i) pa[i] = *(const float4*)(Ap + i * 4);

#pragma unroll 1
  for (int k0 = 0; k0 < 512; k0 += 32) {
    {
      short h[16], l[16];
#pragma unroll
      for (int i = 0; i < 16; ++i) {
        short2 s = split1(((const float*)pa)[i]);
        h[i] = s.x; l[i] = s.y;
      }
      __syncthreads();
      *(bf16x8*)&sAh[sm * 40 + sk]     = *(bf16x8*)&h[0];
      *(bf16x8*)&sAh[sm * 40 + sk + 8] = *(bf16x8*)&h[8];
      *(bf16x8*)&sAl[sm * 40 + sk]     = *(bf16x8*)&l[0];
      *(bf16x8*)&sAl[sm * 40 + sk + 8] = *(bf16x8*)&l[8];
      __syncthreads();
    }

    if (k0 + 32 < 512) {
#pragma unroll
      for (int i = 0; i < 4; ++i) pa[i] = *(const float4*)(Ap + k0 + 32 + i * 4);
    }

    bf16x8 bh[4], bl[4];
#pragma unroll
    for (int nt = 0; nt < 4; ++nt) {
      const float* bp = B + (size_t)(k0 + q * 8) * BATCH + bn + wn + nt * 16 + l15;
      short hh[8], ll[8];
#pragma unroll
      for (int j = 0; j < 8; ++j) {
        short2 s = split1(bp[(size_t)j * BATCH]);
        hh[j] = s.x; ll[j] = s.y;
      }
      bh[nt] = *(bf16x8*)hh;
      bl[nt] = *(bf16x8*)ll;
    }

    bf16x8 ah[4], al[4];
#pragma unroll
    for (int mt = 0; mt < 4; ++mt) {
      const int m = wm + mt * 16 + l15;
      ah[mt] = *(const bf16x8*)&sAh[m * 40 + q * 8];
      al[mt] = *(const bf16x8*)&sAl[m * 40 + q * 8];
    }

#pragma unroll
    for (int mt = 0; mt < 4; ++mt)
#pragma unroll
      for (int nt = 0; nt < 4; ++nt) {
        acc[mt][nt] = __builtin_amdgcn_mfma_f32_16x16x32_bf16(ah[mt], bh[nt], acc[mt][nt], 0, 0, 0);
        acc[mt][nt] = __builtin_amdgcn_mfma_f32_16x16x32_bf16(ah[mt], bl[nt], acc[mt][nt], 0, 0, 0);
        acc[mt][nt] = __builtin_amdgcn_mfma_f32_16x16x32_bf16(al[mt], bh[nt], acc[mt][nt], 0, 0, 0);
      }
  }

#pragma unroll
  for (int mt = 0; mt < 4; ++mt)
#pragma unroll
    for (int nt = 0; nt < 4; ++nt)
#pragma unroll
      for (int r = 0; r < 4; ++r) {
        const int gm = bm + wm + mt * 16 + q * 4 + r;
        const int gn = bn + wn + nt * 16 + l15;
        C[(size_t)gm * BATCH + gn] = acc[mt][nt][r];
      }
}

extern "C" void kernel_launch(void* const* d_in, const int* in_sizes, int n_in,
                              void* d_out, int out_size, void* d_ws, size_t ws_size,
                              hipStream_t stream) {
  const float* x      = (const float*)d_in[0];
  const float* thetas = (const float*)d_in[1];
  const float* phis   = (const float*)d_in[2];
  const float* gammas = (const float*)d_in[3];
  const float* bse    = (const float*)d_in[4];
  const float* lse    = (const float*)d_in[5];

  float* base = (float*)d_ws;
  float4* pp  = (float4*)d_ws;
  const long PPF = 1048576;   // 4 MB in floats
  const long S   = 524288;    // 2 MB in floats

  precomp_kernel<<<512, 256, 0, stream>>>(thetas, phis, bse, lse, pp);

  if (ws_size >= (size_t)24 * 1024 * 1024) {
    // Layout (MB): pp [0,4); compose outs [4,20): T0(bf16^T),T1(f),...,T7;
    //   L1: U0 bf16^T @0, U1 f @20, U2 bf16^T @2, U3 f @22;
    //   L2: V0 bf16^T @4, V1 f @6;  L3: Tf f @0;  xp @ [2,18.8).
    float* B0 = base + PPF;
    compose_band<<<1024, 256, 0, stream>>>(gammas, pp, B0, 32);

    // PROBE (round 10): each merge level launched TWICE (all idempotent —
    // inputs untouched, outputs rewritten identically). Total-duration delta
    // vs the single-launch baseline measures the merge tree's true cost M.
    // REMOVE duplicates next round.
    // L1 (z=0..3): U_z = T(2z+1) * T(2z)
    merge_t<<<dim3(8, 16, 4), 256, 0, stream>>>(
        B0 + S, 2 * S, (const unsigned short*)B0, 4 * S,
        (unsigned short*)base, 2 * S, base + 5 * PPF, S, 68, 68, 0);
    merge_t<<<dim3(8, 16, 4), 256, 0, stream>>>(
        B0 + S, 2 * S, (const unsigned short*)B0, 4 * S,
        (unsigned short*)base, 2 * S, base + 5 * PPF, S, 68, 68, 0);

    // L2 (z=0,1): V0 = U1*U0 (bf16^T @4MB); V1 = U3*U2 (float @6MB)
    merge_t<<<dim3(8, 16, 2), 256, 0, stream>>>(
        base + 5 * PPF, S, (const unsigned short*)base, 2 * S,
        (unsigned short*)(base + PPF), 0, base + PPF + S, 0, 136, 136, 0);
    merge_t<<<dim3(8, 16, 2), 256, 0, stream>>>(
        base + 5 * PPF, S, (const unsigned short*)base, 2 * S,
        (unsigned short*)(base + PPF), 0, base + PPF + S, 0, 136, 136, 0);

    // L3: Tf = V1*V0, float @0 (force float out)
    merge_t<<<dim3(8, 16, 1), 256, 0, stream>>>(
        base + PPF + S, 0, (const unsigned short*)(base + PPF), 0,
        (unsigned short*)base, 0, base, 0, 272, 272, 1);
    merge_t<<<dim3(8, 16, 1), 256, 0, stream>>>(
        base + PPF + S, 0, (const unsigned short*)(base + PPF), 0,
        (unsigned short*)base, 0, base, 0, 272, 272, 1);

    short* xp = (short*)(base + S);
    xprep_kernel<<<2048, 256, 0, stream>>>(x, xp);

    gemm_mfma_packed<<<dim3(64, 8), 256, 0, stream>>>(base, xp, (float*)d_out);
  } else {
    // Legacy plans (float everywhere, verified).
    int nseg;
    if (ws_size >= (size_t)14 * 1024 * 1024)      nseg = 4;
    else if (ws_size >= (size_t)8 * 1024 * 1024)  nseg = 2;
    else                                          nseg = 1;

    float* segs = base + PPF;
    float* Tf;
    compose_kernel<<<nseg * 128, 256, 0, stream>>>(gammas, pp, segs, 256 / nseg);

    if (nseg == 4) {
      float* T10 = base;
      float* T32 = base + S;
      Tf = segs + 4 * S;
      merge_g<<<dim3(8, 16, 2), 256, 0, stream>>>(
          segs + S, segs, T10, 2 * S, 2 * S, S, 132, 132);
      merge_g<<<dim3(8, 16, 1), 256, 0, stream>>>(
          T32, T10, Tf, 0, 0, 0, 264, 264);
    } else if (nseg == 2) {
      Tf = base;
      merge_g<<<dim3(8, 16, 1), 256, 0, stream>>>(
          segs + S, segs, Tf, 0, 0, 0, 260, 260);
    } else {
      Tf = segs;
    }

    gemm_mfma<<<dim3(BATCH / 128, 8), 256, 0, stream>>>(Tf, x, (float*)d_out);
  }
}

// Round 12
// 228.354 us; speedup vs baseline: 1.3327x; 1.3327x over previous
//
#include <hip/hip_runtime.h>
#include <math.h>

#define BATCH 8192
#define NROW 512
#define NCOL 512
#define MNODE 256
#define PL 524288  // ushorts per bf16 plane (512*1024)

typedef __attribute__((ext_vector_type(8))) short bf16x8;
typedef __attribute__((ext_vector_type(4))) short s16x4;
typedef __attribute__((ext_vector_type(4))) float f32x4;

// Split fp32 into truncated-bf16 hi + bf16(lo residual). a ~= hi + lo.
__device__ __forceinline__ short2 split1(float x) {
  unsigned u = __float_as_uint(x);
  short h = (short)(u >> 16);
  float r = x - __uint_as_float(u & 0xffff0000u);
  short l = (short)(__float_as_uint(r) >> 16);
  return make_short2(h, l);
}

// ---------------------------------------------------------------------------
// Fused per-node 2x2 complex matrix (verified).
// ---------------------------------------------------------------------------
__global__ __launch_bounds__(256) void precomp_kernel(
    const float* __restrict__ thetas, const float* __restrict__ phis,
    const float* __restrict__ bse, const float* __restrict__ lse,
    float4* __restrict__ pp) {
  int n = blockIdx.x * 256 + threadIdx.x;
  float th = thetas[n], ph = phis[n];
  float e0 = bse[2 * n + 0], e1 = bse[2 * n + 1];
  float l0 = lse[2 * n + 0], l1 = lse[2 * n + 1];
  const float K = 0.16609640474436813f;  // log2(10)/20
  float ins0 = exp2f(l0 * K), ins1 = exp2f(l1 * K);
  const float PI4 = 0.7853981633974483f;
  float s0, c0, s1, c1, sp, cp, st, ct;
  sincosf(PI4 + e0, &s0, &c0);
  sincosf(PI4 + e1, &s1, &c1);
  sincosf(ph, &sp, &cp);
  sincosf(th, &st, &ct);
  float AL = ins0 * s0, C1L = c0, C2L = ins0 * c0, SL = s0;
  float AR = ins1 * s1, C1R = c1, C2R = ins1 * c1, SR = s1;
  float a11r = AL * cp,   a11i = AL * sp;
  float a12r = 0.f,       a12i = C1L;
  float a21r = -C2L * sp, a21i = C2L * cp;
  float a22r = SL,        a22i = 0.f;
  float b11r = a11r * ct - a11i * st, b11i = a11r * st + a11i * ct;
  float b12r = a12r * ct - a12i * st, b12i = a12r * st + a12i * ct;
  float n11r = AR * b11r - C1R * a21i;
  float n11i = AR * b11i + C1R * a21r;
  float n12r = AR * b12r - C1R * a22i;
  float n12i = AR * b12i + C1R * a22r;
  float n21r = -C2R * b11i + SR * a21r;
  float n21i =  C2R * b11r + SR * a21i;
  float n22r = -C2R * b12i + SR * a22r;
  float n22i =  C2R * b12r + SR * a22i;
  pp[2 * n + 0] = make_float4(n11r, n11i, n12r, n12i);
  pp[2 * n + 1] = make_float4(n21r, n21i, n22r, n22i);
}

__device__ __forceinline__ void proc_pair(float& vtr, float& vti, float& vbr, float& vbi,
                                          const float4 q0, const float4 q1) {
  float tr = q0.x * vtr - q0.y * vti + q0.z * vbr - q0.w * vbi;
  float ti = q0.x * vti + q0.y * vtr + q0.z * vbi + q0.w * vbr;
  float br = q1.x * vtr - q1.y * vti + q1.z * vbr - q1.w * vbi;
  float bi = q1.x * vti + q1.y * vtr + q1.z * vbi + q1.w * vbr;
  vtr = tr; vti = ti; vbr = br; vbi = bi;
}

__device__ __forceinline__ int swz(int b) { return b ^ ((b >> 3) & 7); }

// ---------------------------------------------------------------------------
// BAND-COMPACT COMPOSE (verified round 5) + dual-format epilogue (round 6)
// + load predication (verified round 8).
// ---------------------------------------------------------------------------
__global__ __launch_bounds__(256) void compose_band(
    const float* __restrict__ gammas, const float4* __restrict__ pp,
    float* __restrict__ Tsegs, int P) {
  __shared__ float ep[5120];  // [row(0..511)=re, 512+row=im][5]

  const int tid  = threadIdx.x;
  const int lane = tid & 63;
  const int w    = tid >> 6;
  const int seg  = blockIdx.x >> 7;
  const int g    = blockIdx.x & 127;
  const int col  = g * 4 + w;

  const float4* ps = pp + (size_t)seg * P * 1024;
  float* T = Tsegs + (size_t)seg * (1024 * NROW);

  const int colA = (col - 63) & ~1;        // even, slots [colA, colA+127]
  const int E    = colA + 2 * lane;        // my even row; rows E, E+1
  const int je   = E >> 1;
  const int jeC  = je < 0 ? 0 : (je > 255 ? 255 : je);

  const bool vE  = (E >= 0) && (E <= 510);
  const bool vOT = (E >= 0) && (E <= 508);
  const bool vOB = (E >= 2) && (E <= 510);

  float ar = 0.f, ai = 0.f, br = 0.f, bi = 0.f;
  {
    float vr0 = 1.f, vi0 = 0.f;
    if (seg == 0) {
      float sg, cg;
      sincosf(gammas[col], &sg, &cg);
      vr0 = cg; vi0 = sg;
    }
    if (E == col)     { ar = vr0; ai = vi0; }
    if (E + 1 == col) { br = vr0; bi = vi0; }
  }

  const float4* pe = ps + 2 * jeC;
  const float4* po = ps + 512 + 2 * jeC;

  float sar = 0.f, sai = 0.f, sbr = 0.f, sbi = 0.f;

  for (int p = 0; p < P; ++p) {
    // band predicate: rows (E,E+1) intersect [col-2p-2, col+2p+2], margin 2
    const bool actp = (E >= col - 2 * p - 5) && (E <= col + 2 * p + 4);

    float4 o0, o1;
    if (actp) {
      float4 q0 = pe[0];
      float4 q1 = pe[1];
      o0 = po[0];
      o1 = po[-1];

      // even pair (E, E+1)
      float tr = q0.x * ar - q0.y * ai + q0.z * br - q0.w * bi;
      float ti = q0.x * ai + q0.y * ar + q0.z * bi + q0.w * br;
      float ur = q1.x * ar - q1.y * ai + q1.z * br - q1.w * bi;
      float ui = q1.x * ai + q1.y * ar + q1.z * bi + q1.w * br;
      if (vE) { ar = tr; ai = ti; br = ur; bi = ui; }
    }
    pe += 1024; po += 1024;

    if (p == P - 1) { sar = ar; sai = ai; sbr = br; sbi = bi; }

    // neighbor values post-even (all lanes execute; inactive lanes hold 0)
    float anr = __shfl_down(ar, 1, 64);
    float ani = __shfl_down(ai, 1, 64);
    float bpr = __shfl_up(br, 1, 64);
    float bpi = __shfl_up(bi, 1, 64);
    if (lane == 63) { anr = 0.f; ani = 0.f; }
    if (lane == 0)  { bpr = 0.f; bpi = 0.f; }

    if (actp) {
      float tr = o0.x * br - o0.y * bi + o0.z * anr - o0.w * ani;
      float ti = o0.x * bi + o0.y * br + o0.z * ani + o0.w * anr;
      float ur = o1.x * bpr - o1.y * bpi + o1.z * ar - o1.w * ai;
      float ui = o1.x * bpi + o1.y * bpr + o1.z * ai + o1.w * ar;
      if (vOT) { br = tr; bi = ti; }
      if (vOB) { ar = ur; ai = ui; }
    }
  }

  // spill row (exactly one, final odd phase, closed form)
  int sprow = -1;
  float spr = 0.f, spi = 0.f;
  if ((col & 1) == 0) {
    if (colA + 128 <= 511) {
      sprow = colA + 128;
      float4 w1 = ps[(size_t)(P - 1) * 1024 + 512 + 2 * (colA / 2 + 63) + 1];
      float vtr = __shfl(sbr, 63, 64);
      float vti = __shfl(sbi, 63, 64);
      spr = w1.x * vtr - w1.y * vti;
      spi = w1.x * vti + w1.y * vtr;
    }
  } else {
    if (colA - 1 >= 0) {
      sprow = colA - 1;
      float4 w0 = ps[(size_t)(P - 1) * 1024 + 512 + 2 * (colA / 2 - 1)];
      float vbr = __shfl(sar, 0, 64);
      float vbi = __shfl(sai, 0, 64);
      spr = w0.z * vbr - w0.w * vbi;
      spi = w0.z * vbi + w0.w * vbr;
    }
  }

  // deposit into zeroed transpose buffer
  for (int i = tid; i < 5120; i += 256) ep[i] = 0.f;
  __syncthreads();
  if (E >= 0 && E <= 510) {
    ep[E * 5 + w]         = ar;
    ep[(512 + E) * 5 + w] = ai;
    ep[(E + 1) * 5 + w]   = br;
    ep[(513 + E) * 5 + w] = bi;
  }
  if (lane == 0 && sprow >= 0) {
    ep[sprow * 5 + w]         = spr;
    ep[(512 + sprow) * 5 + w] = spi;
  }
  __syncthreads();

  if (seg & 1) {
    // A-side: normal float [1024][512]
#pragma unroll
    for (int k = 0; k < 4; ++k) {
      const int i = k * 256 + tid;
      *(float4*)(T + (size_t)i * NROW + g * 4) =
          make_float4(ep[i * 5 + 0], ep[i * 5 + 1], ep[i * 5 + 2], ep[i * 5 + 3]);
    }
  } else {
    // B-side: transposed bf16-split planes [n][k]
    unsigned short* Thi = (unsigned short*)T;
    unsigned short* Tlo = Thi + PL;
    const int c  = tid & 3;           // column within block
    const int k0 = (tid >> 2) * 16;   // 16 k-entries per thread
    const int colg = g * 4 + c;
    short hh[16], ll[16];
#pragma unroll
    for (int j = 0; j < 16; ++j) {
      short2 s = split1(ep[(k0 + j) * 5 + c]);
      hh[j] = s.x; ll[j] = s.y;
    }
    *(bf16x8*)&Thi[(size_t)colg * 1024 + k0]     = *(bf16x8*)&hh[0];
    *(bf16x8*)&Thi[(size_t)colg * 1024 + k0 + 8] = *(bf16x8*)&hh[8];
    *(bf16x8*)&Tlo[(size_t)colg * 1024 + k0]     = *(bf16x8*)&ll[0];
    *(bf16x8*)&Tlo[(size_t)colg * 1024 + k0 + 8] = *(bf16x8*)&ll[8];
  }
}

// ---------------------------------------------------------------------------
// MERGE v4 (round 11): BM=32 tiles (2x blocks -> L3 fills the chip),
// double-buffered LDS A-staging (ONE barrier per k-step), global A prefetch
// issued right after the barrier so HBM/L2 latency hides under B loads+MFMA.
// Same split1 of same values, same per-(row,col) k-accumulation order ->
// bit-identical (K-window changes only add/remove exact-zero terms).
// A float normal; B transposed bf16-split planes; dual-format output.
// Grid: (8, 32, z).
// ---------------------------------------------------------------------------
__global__ __launch_bounds__(256) void merge_t(
    const float* __restrict__ Ab, long sA,
    const unsigned short* __restrict__ Bb, long sB,
    unsigned short* __restrict__ Cub, long sCu,
    float* __restrict__ Cfb, long sCf,
    int HA, int HB, int force_f) {
  const int z = blockIdx.z;
  const float* A = Ab + (long)z * sA;
  const unsigned short* B = Bb + (long)z * sB;
  const bool fout = force_f || (z & 1);
  unsigned short* Cu = Cub + (long)(z >> 1) * sCu;
  float*          Cf = Cfb + (long)(z >> 1) * sCf;

  __shared__ short sAh[2][32 * 40], sAl[2][32 * 40];  // double-buffered

  const int tid = threadIdx.x;
  const int lane = tid & 63;
  const int w = tid >> 6;
  const int bm = blockIdx.y * 32;
  const int bn = blockIdx.x * 64;
  const int wm = (w & 1) * 16;
  const int wn = (w >> 1) * 32;
  const int q = lane >> 4;
  const int l15 = lane & 15;

  const int sm  = tid >> 3;        // 0..31 staged row
  const int skf = (tid & 7) * 4;   // 0..28 staged k offset (float4)

  // band-limited K window (block-uniform)
  const int rmin = (blockIdx.y & 15) * 32;
  int klo = rmin - HA;
  {
    int t = bn - HB;
    if (t > klo) klo = t;
    if (klo < 0) klo = 0;
  }
  int khi = rmin + 31 + HA;
  {
    int t = bn + 63 + HB;
    if (t < khi) khi = t;
    if (khi > 511) khi = 511;
  }
  klo &= ~31;

  f32x4 acc[2];
  acc[0] = (f32x4){0.f, 0.f, 0.f, 0.f};
  acc[1] = (f32x4){0.f, 0.f, 0.f, 0.f};

  if (klo <= khi) {
    const int ns = ((khi - klo) >> 5) + 1;
    const int total = 2 * ns;

    // per-h staging source + sign (thread-fixed row gm = bm+sm):
    // h=0 (left):  top -> A+r*512 (sgn +1); !top -> A+(512+r)*512 (sgn +1)
    // h=1 (!left): top -> A+(512+r)*512 (sgn -1); !top -> A+r*512 (sgn +1)
    const int gm = bm + sm;
    const int r = gm & 511;
    const bool top = gm < 512;
    const float* srcA0 = top ? (A + (size_t)r * 512) : (A + (size_t)(512 + r) * 512);
    const float* srcA1 = top ? (A + (size_t)(512 + r) * 512) : (A + (size_t)r * 512);
    const float sgn1 = top ? -1.f : 1.f;

    float4 pv = *(const float4*)(srcA0 + klo + skf);

#pragma unroll 1
    for (int s = 0; s < total; ++s) {
      const int h = (s >= ns) ? 1 : 0;
      const int k0 = klo + ((s - h * ns) << 5);
      const int b = s & 1;

      // split + stage into buf[b] (ONE barrier per step; write of buf[b^1]
      // next iter is ordered against this iter's reads by that barrier)
      {
        const float sg = h ? sgn1 : 1.f;
        float vv[4] = {pv.x, pv.y, pv.z, pv.w};
        short hh[4], ll[4];
#pragma unroll
        for (int i = 0; i < 4; ++i) {
          short2 s2 = split1(sg * vv[i]);
          hh[i] = s2.x; ll[i] = s2.y;
        }
        *(s16x4*)&sAh[b][sm * 40 + skf] = *(s16x4*)hh;
        *(s16x4*)&sAl[b][sm * 40 + skf] = *(s16x4*)ll;
      }
      __syncthreads();

      // prefetch next step's A data (latency spans the compute below)
      if (s + 1 < total) {
        const int h2 = (s + 1 >= ns) ? 1 : 0;
        const int k2 = klo + (((s + 1) - h2 * ns) << 5);
        pv = *(const float4*)((h2 ? srcA1 : srcA0) + k2 + skf);
      }

      const int gkb = h * 512 + k0;

      // B fragments: 2 b128 loads each (pre-split planes)
      bf16x8 bh[2], bl[2];
#pragma unroll
      for (int nt = 0; nt < 2; ++nt) {
        const unsigned short* bp =
            B + (size_t)(bn + wn + nt * 16 + l15) * 1024 + gkb + q * 8;
        bh[nt] = *(const bf16x8*)bp;
        bl[nt] = *(const bf16x8*)(bp + PL);
      }

      // A fragments (wave rows wm+l15)
      const int m = wm + l15;
      bf16x8 ah = *(const bf16x8*)&sAh[b][m * 40 + q * 8];
      bf16x8 al = *(const bf16x8*)&sAl[b][m * 40 + q * 8];

#pragma unroll
      for (int nt = 0; nt < 2; ++nt) {
        acc[nt] = __builtin_amdgcn_mfma_f32_16x16x32_bf16(ah, bh[nt], acc[nt], 0, 0, 0);
        acc[nt] = __builtin_amdgcn_mfma_f32_16x16x32_bf16(ah, bl[nt], acc[nt], 0, 0, 0);
        acc[nt] = __builtin_amdgcn_mfma_f32_16x16x32_bf16(al, bh[nt], acc[nt], 0, 0, 0);
      }
    }
  }

  if (fout) {
#pragma unroll
    for (int nt = 0; nt < 2; ++nt)
#pragma unroll
      for (int rr = 0; rr < 4; ++rr) {
        const int gm = bm + wm + q * 4 + rr;
        const int gn = bn + wn + nt * 16 + l15;
        Cf[(size_t)gm * 512 + gn] = acc[nt][rr];
      }
  } else {
    unsigned short* Chi = Cu;
    unsigned short* Clo = Cu + PL;
#pragma unroll
    for (int nt = 0; nt < 2; ++nt) {
      short hh[4], ll[4];
#pragma unroll
      for (int rr = 0; rr < 4; ++rr) {
        short2 s = split1(acc[nt][rr]);
        hh[rr] = s.x; ll[rr] = s.y;
      }
      const int gm0 = bm + wm + q * 4;
      const int gn  = bn + wn + nt * 16 + l15;
      *(s16x4*)&Chi[(size_t)gn * 1024 + gm0] = *(s16x4*)hh;
      *(s16x4*)&Clo[(size_t)gn * 1024 + gm0] = *(s16x4*)ll;
    }
  }
}

// ---------------------------------------------------------------------------
// LEGACY COMPOSE + MERGE (verified; ws < 24 MB fallback).
// ---------------------------------------------------------------------------
__global__ __launch_bounds__(256) void compose_kernel(
    const float* __restrict__ gammas, const float4* __restrict__ pp,
    float* __restrict__ Tsegs, int pairs_per_seg) {
  __shared__ float4 buf[2][1024];
  float* epf = (float*)buf;

  const int tid  = threadIdx.x;
  const int lane = tid & 63;
  const int w    = tid >> 6;
  const int seg  = blockIdx.x >> 7;
  const int g    = blockIdx.x & 127;
  const int col  = g * 4 + w;
  const int colmin = g * 4;

  const float4* ps = pp + (size_t)seg * pairs_per_seg * 1024;
  float* T = Tsegs + (size_t)seg * (1024 * NROW);

  float vr[8], vi[8];
#pragma unroll
  for (int r = 0; r < 8; ++r) {
    const int row = lane * 8 + r;
    vr[r] = 0.f; vi[r] = 0.f;
    if (row == col) {
      if (seg == 0) {
        float sg, cg;
        sincosf(gammas[row], &sg, &cg);
        vr[r] = cg; vi[r] = sg;
      } else {
        vr[r] = 1.f;
      }
    }
  }

  {
    const int sw = swz(tid);
#pragma unroll
    for (int k = 0; k < 4; ++k)
      buf[0][256 * k + sw] = ps[256 * k + tid];
  }
  __syncthreads();

  const int Lc = col >> 3;

#pragma unroll 1
  for (int p = 0; p < pairs_per_seg; ++p) {
    const int b = p & 1;

    const int HA = (p >> 2) + 3;
    const bool act  = (lane >= Lc - HA)     && (lane <= Lc + HA);
    const bool wide = (lane >= Lc - HA - 1) && (lane <= Lc + HA + 1);

    float4 f0, f1, f2, f3;
    bool st0 = false, st1 = false;
    if (p < pairs_per_seg - 1) {
      const int slo = colmin - 2 * p - 50;
      const int shi = colmin + 2 * p + 53;
      st0 = (tid + 1 >= slo) && (tid <= shi);
      st1 = (tid + 257 >= slo) && (tid + 256 <= shi);
      const float4* src = ps + (size_t)(p + 1) * 1024;
      if (st0) { f0 = src[tid];       f2 = src[512 + tid]; }
      if (st1) { f1 = src[256 + tid]; f3 = src[768 + tid]; }
    }

    float4 pe[8], po[7], pu1;
    if (act) {
      const int base = 8 * lane;
      const int l7 = lane & 7;
#pragma unroll
      for (int j = 0; j < 8; ++j) pe[j] = buf[b][base + (j ^ l7)];
#pragma unroll
      for (int j = 0; j < 7; ++j) po[j] = buf[b][512 + base + (j ^ l7)];
      const int lm = (lane == 0) ? 0 : lane - 1;
      pu1 = buf[b][512 + 8 * lm + (7 ^ (lm & 7))];

#pragma unroll
      for (int k = 0; k < 4; ++k)
        proc_pair(vr[2 * k], vi[2 * k], vr[2 * k + 1], vi[2 * k + 1],
                  pe[2 * k], pe[2 * k + 1]);

#pragma unroll
      for (int k = 0; k < 3; ++k)
        proc_pair(vr[2 * k + 1], vi[2 * k + 1], vr[2 * k + 2], vi[2 * k + 2],
                  po[2 * k], po[2 * k + 1]);
    }

    float br = 0.f, bi = 0.f, tu = 0.f, tv = 0.f;
    if (wide) {
      br = __shfl_down(vr[0], 1, 64);
      bi = __shfl_down(vi[0], 1, 64);
      tu = __shfl_up(vr[7], 1, 64);
      tv = __shfl_up(vi[7], 1, 64);
    }
    if (act) {
      float nAr = po[6].x * vr[7] - po[6].y * vi[7] + po[6].z * br - po[6].w * bi;
      float nAi = po[6].x * vi[7] + po[6].y * vr[7] + po[6].z * bi + po[6].w * br;
      float nBr = pu1.x * tu - pu1.y * tv + pu1.z * vr[0] - pu1.w * vi[0];
      float nBi = pu1.x * tv + pu1.y * tu + pu1.z * vi[0] + pu1.w * vr[0];
      if (lane < 63) { vr[7] = nAr; vi[7] = nAi; }
      if (lane > 0)  { vr[0] = nBr; vi[0] = nBi; }
    }

    if (p < pairs_per_seg - 1) {
      const int sw = swz(tid);
      if (st0) { buf[1 - b][sw] = f0;       buf[1 - b][512 + sw] = f2; }
      if (st1) { buf[1 - b][256 + sw] = f1; buf[1 - b][768 + sw] = f3; }
    }
    __syncthreads();
  }

#pragma unroll
  for (int r = 0; r < 8; ++r) {
    epf[(lane * 8 + r) * 5 + w] = vr[r];
    epf[(512 + lane * 8 + r) * 5 + w] = vi[r];
  }
  __syncthreads();
#pragma unroll
  for (int k = 0; k < 4; ++k) {
    const int i = k * 256 + tid;
    *(float4*)(T + (size_t)i * NROW + g * 4) =
        make_float4(epf[i * 5 + 0], epf[i * 5 + 1], epf[i * 5 + 2], epf[i * 5 + 3]);
  }
}

__global__ __launch_bounds__(256) void merge_g(
    const float* __restrict__ Ab, const float* __restrict__ Bb,
    float* __restrict__ Cb, long sA, long sB, long sC, int HA, int HB) {
  const float* A = Ab + (long)blockIdx.z * sA;
  const float* B = Bb + (long)blockIdx.z * sB;
  float*       C = Cb + (long)blockIdx.z * sC;

  __shared__ short sAh[64 * 40], sAl[64 * 40];

  const int tid = threadIdx.x;
  const int lane = tid & 63;
  const int w = tid >> 6;
  const int bm = blockIdx.y * 64;
  const int bn = blockIdx.x * 64;
  const int wm = (w & 1) * 32;
  const int wn = (w >> 1) * 32;
  const int q = lane >> 4;
  const int l15 = lane & 15;

  const int sm = tid >> 2;
  const int sk = (tid & 3) * 8;

  const int rmin = (blockIdx.y & 7) * 64;
  int klo = rmin - HA;
  {
    int t = bn - HB;
    if (t > klo) klo = t;
    if (klo < 0) klo = 0;
  }
  int khi = rmin + 63 + HA;
  {
    int t = bn + 63 + HB;
    if (t < khi) khi = t;
    if (khi > 511) khi = 511;
  }
  klo &= ~31;

  f32x4 acc[2][2];
#pragma unroll
  for (int i = 0; i < 2; ++i)
#pragma unroll
    for (int j = 0; j < 2; ++j) acc[i][j] = (f32x4){0.f, 0.f, 0.f, 0.f};

  if (klo <= khi) {
#pragma unroll 1
    for (int h = 0; h < 2; ++h) {
#pragma unroll 1
      for (int k0 = klo; k0 <= khi; k0 += 32) {
        const int gkb = h * 512 + k0;
        {
          const int gm = bm + sm;
          const int gk = gkb + sk;
          const int r = gm & 511;
          const bool top = gm < 512;
          const bool left = gk < 512;
          const int col = gk & 511;
          const float* src = (top == left) ? (A + (size_t)r * 512)
                                           : (A + (size_t)(512 + r) * 512);
          const float sgn = (top && !left) ? -1.f : 1.f;
          float4 v0 = *(const float4*)(src + col);
          float4 v1 = *(const float4*)(src + col + 4);
          float vv[8] = {v0.x, v0.y, v0.z, v0.w, v1.x, v1.y, v1.z, v1.w};
          short hh[8], ll[8];
#pragma unroll
          for (int i = 0; i < 8; ++i) {
            short2 s = split1(sgn * vv[i]);
            hh[i] = s.x; ll[i] = s.y;
          }
          __syncthreads();
          *(bf16x8*)&sAh[sm * 40 + sk] = *(bf16x8*)hh;
          *(bf16x8*)&sAl[sm * 40 + sk] = *(bf16x8*)ll;
          __syncthreads();
        }

        bf16x8 bh[2], bl[2];
#pragma unroll
        for (int nt = 0; nt < 2; ++nt) {
          const float* bp = B + (size_t)(gkb + q * 8) * 512 + bn + wn + nt * 16 + l15;
          short hh[8], ll[8];
#pragma unroll
          for (int j = 0; j < 8; ++j) {
            short2 s = split1(bp[(size_t)j * 512]);
            hh[j] = s.x; ll[j] = s.y;
          }
          bh[nt] = *(bf16x8*)hh;
          bl[nt] = *(bf16x8*)ll;
        }

        bf16x8 ah[2], al[2];
#pragma unroll
        for (int mt = 0; mt < 2; ++mt) {
          const int m = wm + mt * 16 + l15;
          ah[mt] = *(const bf16x8*)&sAh[m * 40 + q * 8];
          al[mt] = *(const bf16x8*)&sAl[m * 40 + q * 8];
        }

#pragma unroll
        for (int mt = 0; mt < 2; ++mt)
#pragma unroll
          for (int nt = 0; nt < 2; ++nt) {
            acc[mt][nt] = __builtin_amdgcn_mfma_f32_16x16x32_bf16(ah[mt], bh[nt], acc[mt][nt], 0, 0, 0);
            acc[mt][nt] = __builtin_amdgcn_mfma_f32_16x16x32_bf16(ah[mt], bl[nt], acc[mt][nt], 0, 0, 0);
            acc[mt][nt] = __builtin_amdgcn_mfma_f32_16x16x32_bf16(al[mt], bh[nt], acc[mt][nt], 0, 0, 0);
          }
      }
    }
  }

#pragma unroll
  for (int mt = 0; mt < 2; ++mt)
#pragma unroll
    for (int nt = 0; nt < 2; ++nt)
#pragma unroll
      for (int r = 0; r < 4; ++r) {
        const int gm = bm + wm + mt * 16 + q * 4 + r;
        const int gn = bn + wn + nt * 16 + l15;
        C[(size_t)gm * 512 + gn] = acc[mt][nt][r];
      }
}

// ---------------------------------------------------------------------------
// XPREP: split x[512][8192] into bf16 hi/lo in MFMA-fragment order.
// ---------------------------------------------------------------------------
__global__ __launch_bounds__(256) void xprep_kernel(
    const float* __restrict__ x, short* __restrict__ xp) {
  const int t = blockIdx.x * 256 + threadIdx.x;
  const int n = t & 8191;
  const int g = t >> 13;
  const float* src = x + (size_t)g * 8 * BATCH + n;
  short h[8], l[8];
#pragma unroll
  for (int j = 0; j < 8; ++j) {
    short2 s = split1(src[(size_t)j * BATCH]);
    h[j] = s.x; l[j] = s.y;
  }
  short* dst = xp + (size_t)t * 16;
  *(bf16x8*)dst = *(bf16x8*)h;
  *(bf16x8*)(dst + 8) = *(bf16x8*)l;
}

// ---------------------------------------------------------------------------
// APPLY v4 (verified round 7): BM=128, BN=128, packed-B fragment loads.
// ---------------------------------------------------------------------------
__global__ __launch_bounds__(256) void gemm_mfma_packed(
    const float* __restrict__ A, const short* __restrict__ xp,
    float* __restrict__ C) {
  __shared__ short sAh[128 * 40], sAl[128 * 40];

  const int tid = threadIdx.x;
  const int lane = tid & 63;
  const int w = tid >> 6;
  const int bm = blockIdx.y * 128;
  const int bn = blockIdx.x * 128;
  const int wm = (w & 1) * 64;
  const int wn = (w >> 1) * 64;
  const int q = lane >> 4;
  const int l15 = lane & 15;

  const int sm = tid >> 1;          // 0..127 staged row
  const int sk = (tid & 1) * 16;    // 0 or 16
  const float* Ap = A + (size_t)(bm + sm) * 512 + sk;

  f32x4 acc[4][4];
#pragma unroll
  for (int i = 0; i < 4; ++i)
#pragma unroll
    for (int j = 0; j < 4; ++j) acc[i][j] = (f32x4){0.f, 0.f, 0.f, 0.f};

  // prefetch first A slab (16 floats/thread)
  float4 pa[4];
#pragma unroll
  for (int i = 0; i < 4; ++i) pa[i] = *(const float4*)(Ap + i * 4);

#pragma unroll 1
  for (int k0 = 0; k0 < 512; k0 += 32) {
    // stage A slab
    {
      short h[16], l[16];
#pragma unroll
      for (int i = 0; i < 16; ++i) {
        short2 s = split1(((const float*)pa)[i]);
        h[i] = s.x; l[i] = s.y;
      }
      __syncthreads();
      *(bf16x8*)&sAh[sm * 40 + sk]     = *(bf16x8*)&h[0];
      *(bf16x8*)&sAh[sm * 40 + sk + 8] = *(bf16x8*)&h[8];
      *(bf16x8*)&sAl[sm * 40 + sk]     = *(bf16x8*)&l[0];
      *(bf16x8*)&sAl[sm * 40 + sk + 8] = *(bf16x8*)&l[8];
      __syncthreads();
    }

    // prefetch next A slab
    if (k0 + 32 < 512) {
#pragma unroll
      for (int i = 0; i < 4; ++i) pa[i] = *(const float4*)(Ap + k0 + 32 + i * 4);
    }

    // B fragments: packed coalesced loads
    const int kt = k0 >> 5;
    bf16x8 bh[4], bl[4];
#pragma unroll
    for (int nt = 0; nt < 4; ++nt) {
      const short* bp = xp + (((size_t)(kt * 4 + q)) * BATCH +
                              (bn + wn + nt * 16 + l15)) * 16;
      bh[nt] = *(const bf16x8*)bp;
      bl[nt] = *(const bf16x8*)(bp + 8);
    }

    // A fragments + MFMA (per-mt frag load to bound registers)
#pragma unroll
    for (int mt = 0; mt < 4; ++mt) {
      const int m = wm + mt * 16 + l15;
      bf16x8 ah = *(const bf16x8*)&sAh[m * 40 + q * 8];
      bf16x8 al = *(const bf16x8*)&sAl[m * 40 + q * 8];
#pragma unroll
      for (int nt = 0; nt < 4; ++nt) {
        acc[mt][nt] = __builtin_amdgcn_mfma_f32_16x16x32_bf16(ah, bh[nt], acc[mt][nt], 0, 0, 0);
        acc[mt][nt] = __builtin_amdgcn_mfma_f32_16x16x32_bf16(ah, bl[nt], acc[mt][nt], 0, 0, 0);
        acc[mt][nt] = __builtin_amdgcn_mfma_f32_16x16x32_bf16(al, bh[nt], acc[mt][nt], 0, 0, 0);
      }
    }
  }

  // epilogue: D[row=q*4+r][col=l15] per 16x16 tile
#pragma unroll
  for (int mt = 0; mt < 4; ++mt)
#pragma unroll
    for (int nt = 0; nt < 4; ++nt)
#pragma unroll
      for (int r = 0; r < 4; ++r) {
        const int gm = bm + wm + mt * 16 + q * 4 + r;
        const int gn = bn + wn + nt * 16 + l15;
        C[(size_t)gm * BATCH + gn] = acc[mt][nt][r];
      }
}

// ---------------------------------------------------------------------------
// APPLY v1 (legacy fallback, verified).
// ---------------------------------------------------------------------------
__global__ __launch_bounds__(256) void gemm_mfma(
    const float* __restrict__ A, const float* __restrict__ B,
    float* __restrict__ C) {
  __shared__ short sAh[128 * 40], sAl[128 * 40];

  const int tid = threadIdx.x;
  const int lane = tid & 63;
  const int w = tid >> 6;
  const int bm = blockIdx.y * 128;
  const int bn = blockIdx.x * 128;
  const int wm = (w & 1) * 64;
  const int wn = (w >> 1) * 64;
  const int q = lane >> 4;
  const int l15 = lane & 15;

  const int sm = tid >> 1;
  const int sk = (tid & 1) * 16;
  const float* Ap = A + (size_t)(bm + sm) * 512 + sk;

  f32x4 acc[4][4];
#pragma unroll
  for (int i = 0; i < 4; ++i)
#pragma unroll
    for (int j = 0; j < 4; ++j) acc[i][j] = (f32x4){0.f, 0.f, 0.f, 0.f};

  float4 pa[4];
#pragma unroll
  for (int i = 0; i < 4; ++i) pa[i] = *(const float4*)(Ap + i * 4);

#pragma unroll 1
  for (int k0 = 0; k0 < 512; k0 += 32) {
    {
      short h[16], l[16];
#pragma unroll
      for (int i = 0; i < 16; ++i) {
        short2 s = split1(((const float*)pa)[i]);
        h[i] = s.x; l[i] = s.y;
      }
      __syncthreads();
      *(bf16x8*)&sAh[sm * 40 + sk]     = *(bf16x8*)&h[0];
      *(bf16x8*)&sAh[sm * 40 + sk + 8] = *(bf16x8*)&h[8];
      *(bf16x8*)&sAl[sm * 40 + sk]     = *(bf16x8*)&l[0];
      *(bf16x8*)&sAl[sm * 40 + sk + 8] = *(bf16x8*)&l[8];
      __syncthreads();
    }

    if (k0 + 32 < 512) {
#pragma unroll
      for (int i = 0; i < 4; ++i) pa[i] = *(const float4*)(Ap + k0 + 32 + i * 4);
    }

    bf16x8 bh[4], bl[4];
#pragma unroll
    for (int nt = 0; nt < 4; ++nt) {
      const float* bp = B + (size_t)(k0 + q * 8) * BATCH + bn + wn + nt * 16 + l15;
      short hh[8], ll[8];
#pragma unroll
      for (int j = 0; j < 8; ++j) {
        short2 s = split1(bp[(size_t)j * BATCH]);
        hh[j] = s.x; ll[j] = s.y;
      }
      bh[nt] = *(bf16x8*)hh;
      bl[nt] = *(bf16x8*)ll;
    }

    bf16x8 ah[4], al[4];
#pragma unroll
    for (int mt = 0; mt < 4; ++mt) {
      const int m = wm + mt * 16 + l15;
      ah[mt] = *(const bf16x8*)&sAh[m * 40 + q * 8];
      al[mt] = *(const bf16x8*)&sAl[m * 40 + q * 8];
    }

#pragma unroll
    for (int mt = 0; mt < 4; ++mt)
#pragma unroll
      for (int nt = 0; nt < 4; ++nt) {
        acc[mt][nt] = __builtin_amdgcn_mfma_f32_16x16x32_bf16(ah[mt], bh[nt], acc[mt][nt], 0, 0, 0);
        acc[mt][nt] = __builtin_amdgcn_mfma_f32_16x16x32_bf16(ah[mt], bl[nt], acc[mt][nt], 0, 0, 0);
        acc[mt][nt] = __builtin_amdgcn_mfma_f32_16x16x32_bf16(al[mt], bh[nt], acc[mt][nt], 0, 0, 0);
      }
  }

#pragma unroll
  for (int mt = 0; mt < 4; ++mt)
#pragma unroll
    for (int nt = 0; nt < 4; ++nt)
#pragma unroll
      for (int r = 0; r < 4; ++r) {
        const int gm = bm + wm + mt * 16 + q * 4 + r;
        const int gn = bn + wn + nt * 16 + l15;
        C[(size_t)gm * BATCH + gn] = acc[mt][nt][r];
      }
}

extern "C" void kernel_launch(void* const* d_in, const int* in_sizes, int n_in,
                              void* d_out, int out_size, void* d_ws, size_t ws_size,
                              hipStream_t stream) {
  const float* x      = (const float*)d_in[0];
  const float* thetas = (const float*)d_in[1];
  const float* phis   = (const float*)d_in[2];
  const float* gammas = (const float*)d_in[3];
  const float* bse    = (const float*)d_in[4];
  const float* lse    = (const float*)d_in[5];

  float* base = (float*)d_ws;
  float4* pp  = (float4*)d_ws;
  const long PPF = 1048576;   // 4 MB in floats
  const long S   = 524288;    // 2 MB in floats

  precomp_kernel<<<512, 256, 0, stream>>>(thetas, phis, bse, lse, pp);

  if (ws_size >= (size_t)24 * 1024 * 1024) {
    // Layout (MB): pp [0,4); compose outs [4,20): T0(bf16^T),T1(f),...,T7;
    //   L1: U0 bf16^T @0, U1 f @20, U2 bf16^T @2, U3 f @22;
    //   L2: V0 bf16^T @4, V1 f @6;  L3: Tf f @0;  xp @ [2,18.8).
    float* B0 = base + PPF;
    compose_band<<<1024, 256, 0, stream>>>(gammas, pp, B0, 32);

    // L1 (z=0..3): U_z = T(2z+1) * T(2z)
    merge_t<<<dim3(8, 32, 4), 256, 0, stream>>>(
        B0 + S, 2 * S, (const unsigned short*)B0, 4 * S,
        (unsigned short*)base, 2 * S, base + 5 * PPF, S, 68, 68, 0);

    // L2 (z=0,1): V0 = U1*U0 (bf16^T @4MB); V1 = U3*U2 (float @6MB)
    merge_t<<<dim3(8, 32, 2), 256, 0, stream>>>(
        base + 5 * PPF, S, (const unsigned short*)base, 2 * S,
        (unsigned short*)(base + PPF), 0, base + PPF + S, 0, 136, 136, 0);

    // L3: Tf = V1*V0, float @0 (force float out)
    merge_t<<<dim3(8, 32, 1), 256, 0, stream>>>(
        base + PPF + S, 0, (const unsigned short*)(base + PPF), 0,
        (unsigned short*)base, 0, base, 0, 272, 272, 1);

    short* xp = (short*)(base + S);
    xprep_kernel<<<2048, 256, 0, stream>>>(x, xp);

    gemm_mfma_packed<<<dim3(64, 8), 256, 0, stream>>>(base, xp, (float*)d_out);
  } else {
    // Legacy plans (float everywhere, verified).
    int nseg;
    if (ws_size >= (size_t)14 * 1024 * 1024)      nseg = 4;
    else if (ws_size >= (size_t)8 * 1024 * 1024)  nseg = 2;
    else                                          nseg = 1;

    float* segs = base + PPF;
    float* Tf;
    compose_kernel<<<nseg * 128, 256, 0, stream>>>(gammas, pp, segs, 256 / nseg);

    if (nseg == 4) {
      float* T10 = base;
      float* T32 = base + S;
      Tf = segs + 4 * S;
      merge_g<<<dim3(8, 16, 2), 256, 0, stream>>>(
          segs + S, segs, T10, 2 * S, 2 * S, S, 132, 132);
      merge_g<<<dim3(8, 16, 1), 256, 0, stream>>>(
          T32, T10, Tf, 0, 0, 0, 264, 264);
    } else if (nseg == 2) {
      Tf = base;
      merge_g<<<dim3(8, 16, 1), 256, 0, stream>>>(
          segs + S, segs, Tf, 0, 0, 0, 260, 260);
    } else {
      Tf = segs;
    }

    gemm_mfma<<<dim3(BATCH / 128, 8), 256, 0, stream>>>(Tf, x, (float*)d_out);
  }
}

// Round 15
// 222.424 us; speedup vs baseline: 1.3683x; 1.0267x over previous
//
#include <hip/hip_runtime.h>
#include <math.h>

#define BATCH 8192
#define NROW 512
#define NCOL 512
#define MNODE 256
#define PL 524288  // ushorts per bf16 plane (512*1024)

typedef __attribute__((ext_vector_type(8))) short bf16x8;
typedef __attribute__((ext_vector_type(4))) short s16x4;
typedef __attribute__((ext_vector_type(4))) float f32x4;

// Split fp32 into truncated-bf16 hi + bf16(lo residual). a ~= hi + lo.
__device__ __forceinline__ short2 split1(float x) {
  unsigned u = __float_as_uint(x);
  short h = (short)(u >> 16);
  float r = x - __uint_as_float(u & 0xffff0000u);
  short l = (short)(__float_as_uint(r) >> 16);
  return make_short2(h, l);
}

// ---------------------------------------------------------------------------
// Fused per-node 2x2 complex matrix (verified).
// ---------------------------------------------------------------------------
__global__ __launch_bounds__(256) void precomp_kernel(
    const float* __restrict__ thetas, const float* __restrict__ phis,
    const float* __restrict__ bse, const float* __restrict__ lse,
    float4* __restrict__ pp) {
  int n = blockIdx.x * 256 + threadIdx.x;
  float th = thetas[n], ph = phis[n];
  float e0 = bse[2 * n + 0], e1 = bse[2 * n + 1];
  float l0 = lse[2 * n + 0], l1 = lse[2 * n + 1];
  const float K = 0.16609640474436813f;  // log2(10)/20
  float ins0 = exp2f(l0 * K), ins1 = exp2f(l1 * K);
  const float PI4 = 0.7853981633974483f;
  float s0, c0, s1, c1, sp, cp, st, ct;
  sincosf(PI4 + e0, &s0, &c0);
  sincosf(PI4 + e1, &s1, &c1);
  sincosf(ph, &sp, &cp);
  sincosf(th, &st, &ct);
  float AL = ins0 * s0, C1L = c0, C2L = ins0 * c0, SL = s0;
  float AR = ins1 * s1, C1R = c1, C2R = ins1 * c1, SR = s1;
  float a11r = AL * cp,   a11i = AL * sp;
  float a12r = 0.f,       a12i = C1L;
  float a21r = -C2L * sp, a21i = C2L * cp;
  float a22r = SL,        a22i = 0.f;
  float b11r = a11r * ct - a11i * st, b11i = a11r * st + a11i * ct;
  float b12r = a12r * ct - a12i * st, b12i = a12r * st + a12i * ct;
  float n11r = AR * b11r - C1R * a21i;
  float n11i = AR * b11i + C1R * a21r;
  float n12r = AR * b12r - C1R * a22i;
  float n12i = AR * b12i + C1R * a22r;
  float n21r = -C2R * b11i + SR * a21r;
  float n21i =  C2R * b11r + SR * a21i;
  float n22r = -C2R * b12i + SR * a22r;
  float n22i =  C2R * b12r + SR * a22i;
  pp[2 * n + 0] = make_float4(n11r, n11i, n12r, n12i);
  pp[2 * n + 1] = make_float4(n21r, n21i, n22r, n22i);
}

__device__ __forceinline__ void proc_pair(float& vtr, float& vti, float& vbr, float& vbi,
                                          const float4 q0, const float4 q1) {
  float tr = q0.x * vtr - q0.y * vti + q0.z * vbr - q0.w * vbi;
  float ti = q0.x * vti + q0.y * vtr + q0.z * vbi + q0.w * vbr;
  float br = q1.x * vtr - q1.y * vti + q1.z * vbr - q1.w * vbi;
  float bi = q1.x * vti + q1.y * vtr + q1.z * vbi + q1.w * vbr;
  vtr = tr; vti = ti; vbr = br; vbi = bi;
}

__device__ __forceinline__ int swz(int b) { return b ^ ((b >> 3) & 7); }

// ---------------------------------------------------------------------------
// BAND-COMPACT COMPOSE (verified round 5) + dual-format epilogue (round 6)
// + load predication (verified round 8).
// ---------------------------------------------------------------------------
__global__ __launch_bounds__(256) void compose_band(
    const float* __restrict__ gammas, const float4* __restrict__ pp,
    float* __restrict__ Tsegs, int P) {
  __shared__ float ep[5120];  // [row(0..511)=re, 512+row=im][5]

  const int tid  = threadIdx.x;
  const int lane = tid & 63;
  const int w    = tid >> 6;
  const int seg  = blockIdx.x >> 7;
  const int g    = blockIdx.x & 127;
  const int col  = g * 4 + w;

  const float4* ps = pp + (size_t)seg * P * 1024;
  float* T = Tsegs + (size_t)seg * (1024 * NROW);

  const int colA = (col - 63) & ~1;        // even, slots [colA, colA+127]
  const int E    = colA + 2 * lane;        // my even row; rows E, E+1
  const int je   = E >> 1;
  const int jeC  = je < 0 ? 0 : (je > 255 ? 255 : je);

  const bool vE  = (E >= 0) && (E <= 510);
  const bool vOT = (E >= 0) && (E <= 508);
  const bool vOB = (E >= 2) && (E <= 510);

  float ar = 0.f, ai = 0.f, br = 0.f, bi = 0.f;
  {
    float vr0 = 1.f, vi0 = 0.f;
    if (seg == 0) {
      float sg, cg;
      sincosf(gammas[col], &sg, &cg);
      vr0 = cg; vi0 = sg;
    }
    if (E == col)     { ar = vr0; ai = vi0; }
    if (E + 1 == col) { br = vr0; bi = vi0; }
  }

  const float4* pe = ps + 2 * jeC;
  const float4* po = ps + 512 + 2 * jeC;

  float sar = 0.f, sai = 0.f, sbr = 0.f, sbi = 0.f;

  for (int p = 0; p < P; ++p) {
    // band predicate: rows (E,E+1) intersect [col-2p-2, col+2p+2], margin 2
    const bool actp = (E >= col - 2 * p - 5) && (E <= col + 2 * p + 4);

    float4 o0, o1;
    if (actp) {
      float4 q0 = pe[0];
      float4 q1 = pe[1];
      o0 = po[0];
      o1 = po[-1];

      // even pair (E, E+1)
      float tr = q0.x * ar - q0.y * ai + q0.z * br - q0.w * bi;
      float ti = q0.x * ai + q0.y * ar + q0.z * bi + q0.w * br;
      float ur = q1.x * ar - q1.y * ai + q1.z * br - q1.w * bi;
      float ui = q1.x * ai + q1.y * ar + q1.z * bi + q1.w * br;
      if (vE) { ar = tr; ai = ti; br = ur; bi = ui; }
    }
    pe += 1024; po += 1024;

    if (p == P - 1) { sar = ar; sai = ai; sbr = br; sbi = bi; }

    // neighbor values post-even (all lanes execute; inactive lanes hold 0)
    float anr = __shfl_down(ar, 1, 64);
    float ani = __shfl_down(ai, 1, 64);
    float bpr = __shfl_up(br, 1, 64);
    float bpi = __shfl_up(bi, 1, 64);
    if (lane == 63) { anr = 0.f; ani = 0.f; }
    if (lane == 0)  { bpr = 0.f; bpi = 0.f; }

    if (actp) {
      float tr = o0.x * br - o0.y * bi + o0.z * anr - o0.w * ani;
      float ti = o0.x * bi + o0.y * br + o0.z * ani + o0.w * anr;
      float ur = o1.x * bpr - o1.y * bpi + o1.z * ar - o1.w * ai;
      float ui = o1.x * bpi + o1.y * bpr + o1.z * ai + o1.w * ar;
      if (vOT) { br = tr; bi = ti; }
      if (vOB) { ar = ur; ai = ui; }
    }
  }

  // spill row (exactly one, final odd phase, closed form)
  int sprow = -1;
  float spr = 0.f, spi = 0.f;
  if ((col & 1) == 0) {
    if (colA + 128 <= 511) {
      sprow = colA + 128;
      float4 w1 = ps[(size_t)(P - 1) * 1024 + 512 + 2 * (colA / 2 + 63) + 1];
      float vtr = __shfl(sbr, 63, 64);
      float vti = __shfl(sbi, 63, 64);
      spr = w1.x * vtr - w1.y * vti;
      spi = w1.x * vti + w1.y * vtr;
    }
  } else {
    if (colA - 1 >= 0) {
      sprow = colA - 1;
      float4 w0 = ps[(size_t)(P - 1) * 1024 + 512 + 2 * (colA / 2 - 1)];
      float vbr = __shfl(sar, 0, 64);
      float vbi = __shfl(sai, 0, 64);
      spr = w0.z * vbr - w0.w * vbi;
      spi = w0.z * vbi + w0.w * vbr;
    }
  }

  // deposit into zeroed transpose buffer
  for (int i = tid; i < 5120; i += 256) ep[i] = 0.f;
  __syncthreads();
  if (E >= 0 && E <= 510) {
    ep[E * 5 + w]         = ar;
    ep[(512 + E) * 5 + w] = ai;
    ep[(E + 1) * 5 + w]   = br;
    ep[(513 + E) * 5 + w] = bi;
  }
  if (lane == 0 && sprow >= 0) {
    ep[sprow * 5 + w]         = spr;
    ep[(512 + sprow) * 5 + w] = spi;
  }
  __syncthreads();

  if (seg & 1) {
    // A-side: normal float [1024][512]
#pragma unroll
    for (int k = 0; k < 4; ++k) {
      const int i = k * 256 + tid;
      *(float4*)(T + (size_t)i * NROW + g * 4) =
          make_float4(ep[i * 5 + 0], ep[i * 5 + 1], ep[i * 5 + 2], ep[i * 5 + 3]);
    }
  } else {
    // B-side: transposed bf16-split planes [n][k]
    unsigned short* Thi = (unsigned short*)T;
    unsigned short* Tlo = Thi + PL;
    const int c  = tid & 3;           // column within block
    const int k0 = (tid >> 2) * 16;   // 16 k-entries per thread
    const int colg = g * 4 + c;
    short hh[16], ll[16];
#pragma unroll
    for (int j = 0; j < 16; ++j) {
      short2 s = split1(ep[(k0 + j) * 5 + c]);
      hh[j] = s.x; ll[j] = s.y;
    }
    *(bf16x8*)&Thi[(size_t)colg * 1024 + k0]     = *(bf16x8*)&hh[0];
    *(bf16x8*)&Thi[(size_t)colg * 1024 + k0 + 8] = *(bf16x8*)&hh[8];
    *(bf16x8*)&Tlo[(size_t)colg * 1024 + k0]     = *(bf16x8*)&ll[0];
    *(bf16x8*)&Tlo[(size_t)colg * 1024 + k0 + 8] = *(bf16x8*)&ll[8];
  }
}

// ---------------------------------------------------------------------------
// MERGE v4 (verified round 12): BM=32 tiles, double-buffered LDS A-staging
// (one barrier per k-step), global A prefetch. A float normal; B transposed
// bf16-split planes; dual-format output. Grid: (8, 32, z).
// ---------------------------------------------------------------------------
__global__ __launch_bounds__(256) void merge_t(
    const float* __restrict__ Ab, long sA,
    const unsigned short* __restrict__ Bb, long sB,
    unsigned short* __restrict__ Cub, long sCu,
    float* __restrict__ Cfb, long sCf,
    int HA, int HB, int force_f) {
  const int z = blockIdx.z;
  const float* A = Ab + (long)z * sA;
  const unsigned short* B = Bb + (long)z * sB;
  const bool fout = force_f || (z & 1);
  unsigned short* Cu = Cub + (long)(z >> 1) * sCu;
  float*          Cf = Cfb + (long)(z >> 1) * sCf;

  __shared__ short sAh[2][32 * 40], sAl[2][32 * 40];  // double-buffered

  const int tid = threadIdx.x;
  const int lane = tid & 63;
  const int w = tid >> 6;
  const int bm = blockIdx.y * 32;
  const int bn = blockIdx.x * 64;
  const int wm = (w & 1) * 16;
  const int wn = (w >> 1) * 32;
  const int q = lane >> 4;
  const int l15 = lane & 15;

  const int sm  = tid >> 3;        // 0..31 staged row
  const int skf = (tid & 7) * 4;   // 0..28 staged k offset (float4)

  // band-limited K window (block-uniform)
  const int rmin = (blockIdx.y & 15) * 32;
  int klo = rmin - HA;
  {
    int t = bn - HB;
    if (t > klo) klo = t;
    if (klo < 0) klo = 0;
  }
  int khi = rmin + 31 + HA;
  {
    int t = bn + 63 + HB;
    if (t < khi) khi = t;
    if (khi > 511) khi = 511;
  }
  klo &= ~31;

  f32x4 acc[2];
  acc[0] = (f32x4){0.f, 0.f, 0.f, 0.f};
  acc[1] = (f32x4){0.f, 0.f, 0.f, 0.f};

  if (klo <= khi) {
    const int ns = ((khi - klo) >> 5) + 1;
    const int total = 2 * ns;

    const int gm = bm + sm;
    const int r = gm & 511;
    const bool top = gm < 512;
    const float* srcA0 = top ? (A + (size_t)r * 512) : (A + (size_t)(512 + r) * 512);
    const float* srcA1 = top ? (A + (size_t)(512 + r) * 512) : (A + (size_t)r * 512);
    const float sgn1 = top ? -1.f : 1.f;

    float4 pv = *(const float4*)(srcA0 + klo + skf);

#pragma unroll 1
    for (int s = 0; s < total; ++s) {
      const int h = (s >= ns) ? 1 : 0;
      const int k0 = klo + ((s - h * ns) << 5);
      const int b = s & 1;

      // split + stage into buf[b] (ONE barrier per step)
      {
        const float sg = h ? sgn1 : 1.f;
        float vv[4] = {pv.x, pv.y, pv.z, pv.w};
        short hh[4], ll[4];
#pragma unroll
        for (int i = 0; i < 4; ++i) {
          short2 s2 = split1(sg * vv[i]);
          hh[i] = s2.x; ll[i] = s2.y;
        }
        *(s16x4*)&sAh[b][sm * 40 + skf] = *(s16x4*)hh;
        *(s16x4*)&sAl[b][sm * 40 + skf] = *(s16x4*)ll;
      }
      __syncthreads();

      // prefetch next step's A data (latency spans the compute below)
      if (s + 1 < total) {
        const int h2 = (s + 1 >= ns) ? 1 : 0;
        const int k2 = klo + (((s + 1) - h2 * ns) << 5);
        pv = *(const float4*)((h2 ? srcA1 : srcA0) + k2 + skf);
      }

      const int gkb = h * 512 + k0;

      // B fragments: 2 b128 loads each (pre-split planes)
      bf16x8 bh[2], bl[2];
#pragma unroll
      for (int nt = 0; nt < 2; ++nt) {
        const unsigned short* bp =
            B + (size_t)(bn + wn + nt * 16 + l15) * 1024 + gkb + q * 8;
        bh[nt] = *(const bf16x8*)bp;
        bl[nt] = *(const bf16x8*)(bp + PL);
      }

      // A fragments (wave rows wm+l15)
      const int m = wm + l15;
      bf16x8 ah = *(const bf16x8*)&sAh[b][m * 40 + q * 8];
      bf16x8 al = *(const bf16x8*)&sAl[b][m * 40 + q * 8];

#pragma unroll
      for (int nt = 0; nt < 2; ++nt) {
        acc[nt] = __builtin_amdgcn_mfma_f32_16x16x32_bf16(ah, bh[nt], acc[nt], 0, 0, 0);
        acc[nt] = __builtin_amdgcn_mfma_f32_16x16x32_bf16(ah, bl[nt], acc[nt], 0, 0, 0);
        acc[nt] = __builtin_amdgcn_mfma_f32_16x16x32_bf16(al, bh[nt], acc[nt], 0, 0, 0);
      }
    }
  }

  if (fout) {
#pragma unroll
    for (int nt = 0; nt < 2; ++nt)
#pragma unroll
      for (int rr = 0; rr < 4; ++rr) {
        const int gm = bm + wm + q * 4 + rr;
        const int gn = bn + wn + nt * 16 + l15;
        Cf[(size_t)gm * 512 + gn] = acc[nt][rr];
      }
  } else {
    unsigned short* Chi = Cu;
    unsigned short* Clo = Cu + PL;
#pragma unroll
    for (int nt = 0; nt < 2; ++nt) {
      short hh[4], ll[4];
#pragma unroll
      for (int rr = 0; rr < 4; ++rr) {
        short2 s = split1(acc[nt][rr]);
        hh[rr] = s.x; ll[rr] = s.y;
      }
      const int gm0 = bm + wm + q * 4;
      const int gn  = bn + wn + nt * 16 + l15;
      *(s16x4*)&Chi[(size_t)gn * 1024 + gm0] = *(s16x4*)hh;
      *(s16x4*)&Clo[(size_t)gn * 1024 + gm0] = *(s16x4*)ll;
    }
  }
}

// ---------------------------------------------------------------------------
// LEGACY COMPOSE + MERGE (verified; ws < 24 MB fallback).
// ---------------------------------------------------------------------------
__global__ __launch_bounds__(256) void compose_kernel(
    const float* __restrict__ gammas, const float4* __restrict__ pp,
    float* __restrict__ Tsegs, int pairs_per_seg) {
  __shared__ float4 buf[2][1024];
  float* epf = (float*)buf;

  const int tid  = threadIdx.x;
  const int lane = tid & 63;
  const int w    = tid >> 6;
  const int seg  = blockIdx.x >> 7;
  const int g    = blockIdx.x & 127;
  const int col  = g * 4 + w;
  const int colmin = g * 4;

  const float4* ps = pp + (size_t)seg * pairs_per_seg * 1024;
  float* T = Tsegs + (size_t)seg * (1024 * NROW);

  float vr[8], vi[8];
#pragma unroll
  for (int r = 0; r < 8; ++r) {
    const int row = lane * 8 + r;
    vr[r] = 0.f; vi[r] = 0.f;
    if (row == col) {
      if (seg == 0) {
        float sg, cg;
        sincosf(gammas[row], &sg, &cg);
        vr[r] = cg; vi[r] = sg;
      } else {
        vr[r] = 1.f;
      }
    }
  }

  {
    const int sw = swz(tid);
#pragma unroll
    for (int k = 0; k < 4; ++k)
      buf[0][256 * k + sw] = ps[256 * k + tid];
  }
  __syncthreads();

  const int Lc = col >> 3;

#pragma unroll 1
  for (int p = 0; p < pairs_per_seg; ++p) {
    const int b = p & 1;

    const int HA = (p >> 2) + 3;
    const bool act  = (lane >= Lc - HA)     && (lane <= Lc + HA);
    const bool wide = (lane >= Lc - HA - 1) && (lane <= Lc + HA + 1);

    float4 f0, f1, f2, f3;
    bool st0 = false, st1 = false;
    if (p < pairs_per_seg - 1) {
      const int slo = colmin - 2 * p - 50;
      const int shi = colmin + 2 * p + 53;
      st0 = (tid + 1 >= slo) && (tid <= shi);
      st1 = (tid + 257 >= slo) && (tid + 256 <= shi);
      const float4* src = ps + (size_t)(p + 1) * 1024;
      if (st0) { f0 = src[tid];       f2 = src[512 + tid]; }
      if (st1) { f1 = src[256 + tid]; f3 = src[768 + tid]; }
    }

    float4 pe[8], po[7], pu1;
    if (act) {
      const int base = 8 * lane;
      const int l7 = lane & 7;
#pragma unroll
      for (int j = 0; j < 8; ++j) pe[j] = buf[b][base + (j ^ l7)];
#pragma unroll
      for (int j = 0; j < 7; ++j) po[j] = buf[b][512 + base + (j ^ l7)];
      const int lm = (lane == 0) ? 0 : lane - 1;
      pu1 = buf[b][512 + 8 * lm + (7 ^ (lm & 7))];

#pragma unroll
      for (int k = 0; k < 4; ++k)
        proc_pair(vr[2 * k], vi[2 * k], vr[2 * k + 1], vi[2 * k + 1],
                  pe[2 * k], pe[2 * k + 1]);

#pragma unroll
      for (int k = 0; k < 3; ++k)
        proc_pair(vr[2 * k + 1], vi[2 * k + 1], vr[2 * k + 2], vi[2 * k + 2],
                  po[2 * k], po[2 * k + 1]);
    }

    float br = 0.f, bi = 0.f, tu = 0.f, tv = 0.f;
    if (wide) {
      br = __shfl_down(vr[0], 1, 64);
      bi = __shfl_down(vi[0], 1, 64);
      tu = __shfl_up(vr[7], 1, 64);
      tv = __shfl_up(vi[7], 1, 64);
    }
    if (act) {
      float nAr = po[6].x * vr[7] - po[6].y * vi[7] + po[6].z * br - po[6].w * bi;
      float nAi = po[6].x * vi[7] + po[6].y * vr[7] + po[6].z * bi + po[6].w * br;
      float nBr = pu1.x * tu - pu1.y * tv + pu1.z * vr[0] - pu1.w * vi[0];
      float nBi = pu1.x * tv + pu1.y * tu + pu1.z * vi[0] + pu1.w * vr[0];
      if (lane < 63) { vr[7] = nAr; vi[7] = nAi; }
      if (lane > 0)  { vr[0] = nBr; vi[0] = nBi; }
    }

    if (p < pairs_per_seg - 1) {
      const int sw = swz(tid);
      if (st0) { buf[1 - b][sw] = f0;       buf[1 - b][512 + sw] = f2; }
      if (st1) { buf[1 - b][256 + sw] = f1; buf[1 - b][768 + sw] = f3; }
    }
    __syncthreads();
  }

#pragma unroll
  for (int r = 0; r < 8; ++r) {
    epf[(lane * 8 + r) * 5 + w] = vr[r];
    epf[(512 + lane * 8 + r) * 5 + w] = vi[r];
  }
  __syncthreads();
#pragma unroll
  for (int k = 0; k < 4; ++k) {
    const int i = k * 256 + tid;
    *(float4*)(T + (size_t)i * NROW + g * 4) =
        make_float4(epf[i * 5 + 0], epf[i * 5 + 1], epf[i * 5 + 2], epf[i * 5 + 3]);
  }
}

__global__ __launch_bounds__(256) void merge_g(
    const float* __restrict__ Ab, const float* __restrict__ Bb,
    float* __restrict__ Cb, long sA, long sB, long sC, int HA, int HB) {
  const float* A = Ab + (long)blockIdx.z * sA;
  const float* B = Bb + (long)blockIdx.z * sB;
  float*       C = Cb + (long)blockIdx.z * sC;

  __shared__ short sAh[64 * 40], sAl[64 * 40];

  const int tid = threadIdx.x;
  const int lane = tid & 63;
  const int w = tid >> 6;
  const int bm = blockIdx.y * 64;
  const int bn = blockIdx.x * 64;
  const int wm = (w & 1) * 32;
  const int wn = (w >> 1) * 32;
  const int q = lane >> 4;
  const int l15 = lane & 15;

  const int sm = tid >> 2;
  const int sk = (tid & 3) * 8;

  const int rmin = (blockIdx.y & 7) * 64;
  int klo = rmin - HA;
  {
    int t = bn - HB;
    if (t > klo) klo = t;
    if (klo < 0) klo = 0;
  }
  int khi = rmin + 63 + HA;
  {
    int t = bn + 63 + HB;
    if (t < khi) khi = t;
    if (khi > 511) khi = 511;
  }
  klo &= ~31;

  f32x4 acc[2][2];
#pragma unroll
  for (int i = 0; i < 2; ++i)
#pragma unroll
    for (int j = 0; j < 2; ++j) acc[i][j] = (f32x4){0.f, 0.f, 0.f, 0.f};

  if (klo <= khi) {
#pragma unroll 1
    for (int h = 0; h < 2; ++h) {
#pragma unroll 1
      for (int k0 = klo; k0 <= khi; k0 += 32) {
        const int gkb = h * 512 + k0;
        {
          const int gm = bm + sm;
          const int gk = gkb + sk;
          const int r = gm & 511;
          const bool top = gm < 512;
          const bool left = gk < 512;
          const int col = gk & 511;
          const float* src = (top == left) ? (A + (size_t)r * 512)
                                           : (A + (size_t)(512 + r) * 512);
          const float sgn = (top && !left) ? -1.f : 1.f;
          float4 v0 = *(const float4*)(src + col);
          float4 v1 = *(const float4*)(src + col + 4);
          float vv[8] = {v0.x, v0.y, v0.z, v0.w, v1.x, v1.y, v1.z, v1.w};
          short hh[8], ll[8];
#pragma unroll
          for (int i = 0; i < 8; ++i) {
            short2 s = split1(sgn * vv[i]);
            hh[i] = s.x; ll[i] = s.y;
          }
          __syncthreads();
          *(bf16x8*)&sAh[sm * 40 + sk] = *(bf16x8*)hh;
          *(bf16x8*)&sAl[sm * 40 + sk] = *(bf16x8*)ll;
          __syncthreads();
        }

        bf16x8 bh[2], bl[2];
#pragma unroll
        for (int nt = 0; nt < 2; ++nt) {
          const float* bp = B + (size_t)(gkb + q * 8) * 512 + bn + wn + nt * 16 + l15;
          short hh[8], ll[8];
#pragma unroll
          for (int j = 0; j < 8; ++j) {
            short2 s = split1(bp[(size_t)j * 512]);
            hh[j] = s.x; ll[j] = s.y;
          }
          bh[nt] = *(bf16x8*)hh;
          bl[nt] = *(bf16x8*)ll;
        }

        bf16x8 ah[2], al[2];
#pragma unroll
        for (int mt = 0; mt < 2; ++mt) {
          const int m = wm + mt * 16 + l15;
          ah[mt] = *(const bf16x8*)&sAh[m * 40 + q * 8];
          al[mt] = *(const bf16x8*)&sAl[m * 40 + q * 8];
        }

#pragma unroll
        for (int mt = 0; mt < 2; ++mt)
#pragma unroll
          for (int nt = 0; nt < 2; ++nt) {
            acc[mt][nt] = __builtin_amdgcn_mfma_f32_16x16x32_bf16(ah[mt], bh[nt], acc[mt][nt], 0, 0, 0);
            acc[mt][nt] = __builtin_amdgcn_mfma_f32_16x16x32_bf16(ah[mt], bl[nt], acc[mt][nt], 0, 0, 0);
            acc[mt][nt] = __builtin_amdgcn_mfma_f32_16x16x32_bf16(al[mt], bh[nt], acc[mt][nt], 0, 0, 0);
          }
      }
    }
  }

#pragma unroll
  for (int mt = 0; mt < 2; ++mt)
#pragma unroll
    for (int nt = 0; nt < 2; ++nt)
#pragma unroll
      for (int r = 0; r < 4; ++r) {
        const int gm = bm + wm + mt * 16 + q * 4 + r;
        const int gn = bn + wn + nt * 16 + l15;
        C[(size_t)gm * 512 + gn] = acc[mt][nt][r];
      }
}

// ---------------------------------------------------------------------------
// APPLY v1 (verified rounds 0-1): C[1024x8192] = Tf[1024x512] * x[512x8192].
// A staged in LDS (bf16 hi/lo, stride 40); B gathered per-lane from global
// (k-stride dwords, L2-resident) + in-reg split. BM=BN=128, BK=32.
// Removing the xprep dispatch (round 15): r1<->r3 showed xprep+packed vs
// this direct path is neutral, and r10 measured ~13 us/dispatch fixed cost
// -> net win expected from one fewer dispatch.
// ---------------------------------------------------------------------------
__global__ __launch_bounds__(256) void gemm_mfma(
    const float* __restrict__ A, const float* __restrict__ B,
    float* __restrict__ C) {
  __shared__ short sAh[128 * 40], sAl[128 * 40];

  const int tid = threadIdx.x;
  const int lane = tid & 63;
  const int w = tid >> 6;
  const int bm = blockIdx.y * 128;
  const int bn = blockIdx.x * 128;
  const int wm = (w & 1) * 64;
  const int wn = (w >> 1) * 64;
  const int q = lane >> 4;
  const int l15 = lane & 15;

  const int sm = tid >> 1;
  const int sk = (tid & 1) * 16;
  const float* Ap = A + (size_t)(bm + sm) * 512 + sk;

  f32x4 acc[4][4];
#pragma unroll
  for (int i = 0; i < 4; ++i)
#pragma unroll
    for (int j = 0; j < 4; ++j) acc[i][j] = (f32x4){0.f, 0.f, 0.f, 0.f};

  float4 pa[4];
#pragma unroll
  for (int i = 0; i < 4; ++i) pa[i] = *(const float4*)(Ap + i * 4);

#pragma unroll 1
  for (int k0 = 0; k0 < 512; k0 += 32) {
    {
      short h[16], l[16];
#pragma unroll
      for (int i = 0; i < 16; ++i) {
        short2 s = split1(((const float*)pa)[i]);
        h[i] = s.x; l[i] = s.y;
      }
      __syncthreads();
      *(bf16x8*)&sAh[sm * 40 + sk]     = *(bf16x8*)&h[0];
      *(bf16x8*)&sAh[sm * 40 + sk + 8] = *(bf16x8*)&h[8];
      *(bf16x8*)&sAl[sm * 40 + sk]     = *(bf16x8*)&l[0];
      *(bf16x8*)&sAl[sm * 40 + sk + 8] = *(bf16x8*)&l[8];
      __syncthreads();
    }

    if (k0 + 32 < 512) {
#pragma unroll
      for (int i = 0; i < 4; ++i) pa[i] = *(const float4*)(Ap + k0 + 32 + i * 4);
    }

    bf16x8 bh[4], bl[4];
#pragma unroll
    for (int nt = 0; nt < 4; ++nt) {
      const float* bp = B + (size_t)(k0 + q * 8) * BATCH + bn + wn + nt * 16 + l15;
      short hh[8], ll[8];
#pragma unroll
      for (int j = 0; j < 8; ++j) {
        short2 s = split1(bp[(size_t)j * BATCH]);
        hh[j] = s.x; ll[j] = s.y;
      }
      bh[nt] = *(bf16x8*)hh;
      bl[nt] = *(bf16x8*)ll;
    }

    bf16x8 ah[4], al[4];
#pragma unroll
    for (int mt = 0; mt < 4; ++mt) {
      const int m = wm + mt * 16 + l15;
      ah[mt] = *(const bf16x8*)&sAh[m * 40 + q * 8];
      al[mt] = *(const bf16x8*)&sAl[m * 40 + q * 8];
    }

#pragma unroll
    for (int mt = 0; mt < 4; ++mt)
#pragma unroll
      for (int nt = 0; nt < 4; ++nt) {
        acc[mt][nt] = __builtin_amdgcn_mfma_f32_16x16x32_bf16(ah[mt], bh[nt], acc[mt][nt], 0, 0, 0);
        acc[mt][nt] = __builtin_amdgcn_mfma_f32_16x16x32_bf16(ah[mt], bl[nt], acc[mt][nt], 0, 0, 0);
        acc[mt][nt] = __builtin_amdgcn_mfma_f32_16x16x32_bf16(al[mt], bh[nt], acc[mt][nt], 0, 0, 0);
      }
  }

#pragma unroll
  for (int mt = 0; mt < 4; ++mt)
#pragma unroll
    for (int nt = 0; nt < 4; ++nt)
#pragma unroll
      for (int r = 0; r < 4; ++r) {
        const int gm = bm + wm + mt * 16 + q * 4 + r;
        const int gn = bn + wn + nt * 16 + l15;
        C[(size_t)gm * BATCH + gn] = acc[mt][nt][r];
      }
}

extern "C" void kernel_launch(void* const* d_in, const int* in_sizes, int n_in,
                              void* d_out, int out_size, void* d_ws, size_t ws_size,
                              hipStream_t stream) {
  const float* x      = (const float*)d_in[0];
  const float* thetas = (const float*)d_in[1];
  const float* phis   = (const float*)d_in[2];
  const float* gammas = (const float*)d_in[3];
  const float* bse    = (const float*)d_in[4];
  const float* lse    = (const float*)d_in[5];

  float* base = (float*)d_ws;
  float4* pp  = (float4*)d_ws;
  const long PPF = 1048576;   // 4 MB in floats
  const long S   = 524288;    // 2 MB in floats

  precomp_kernel<<<512, 256, 0, stream>>>(thetas, phis, bse, lse, pp);

  if (ws_size >= (size_t)24 * 1024 * 1024) {
    // Layout (MB): pp [0,4); compose outs [4,20): T0(bf16^T),T1(f),...,T7;
    //   L1: U0 bf16^T @0, U1 f @20, U2 bf16^T @2, U3 f @22;
    //   L2: V0 bf16^T @4, V1 f @6;  L3: Tf f @0.
    float* B0 = base + PPF;
    compose_band<<<1024, 256, 0, stream>>>(gammas, pp, B0, 32);

    // L1 (z=0..3): U_z = T(2z+1) * T(2z)
    merge_t<<<dim3(8, 32, 4), 256, 0, stream>>>(
        B0 + S, 2 * S, (const unsigned short*)B0, 4 * S,
        (unsigned short*)base, 2 * S, base + 5 * PPF, S, 68, 68, 0);

    // L2 (z=0,1): V0 = U1*U0 (bf16^T @4MB); V1 = U3*U2 (float @6MB)
    merge_t<<<dim3(8, 32, 2), 256, 0, stream>>>(
        base + 5 * PPF, S, (const unsigned short*)base, 2 * S,
        (unsigned short*)(base + PPF), 0, base + PPF + S, 0, 136, 136, 0);

    // L3: Tf = V1*V0, float @0 (force float out)
    merge_t<<<dim3(8, 32, 1), 256, 0, stream>>>(
        base + PPF + S, 0, (const unsigned short*)(base + PPF), 0,
        (unsigned short*)base, 0, base, 0, 272, 272, 1);

    // Final apply directly from x (no xprep dispatch).
    gemm_mfma<<<dim3(BATCH / 128, 8), 256, 0, stream>>>(base, x, (float*)d_out);
  } else {
    // Legacy plans (float everywhere, verified).
    int nseg;
    if (ws_size >= (size_t)14 * 1024 * 1024)      nseg = 4;
    else if (ws_size >= (size_t)8 * 1024 * 1024)  nseg = 2;
    else                                          nseg = 1;

    float* segs = base + PPF;
    float* Tf;
    compose_kernel<<<nseg * 128, 256, 0, stream>>>(gammas, pp, segs, 256 / nseg);

    if (nseg == 4) {
      float* T10 = base;
      float* T32 = base + S;
      Tf = segs + 4 * S;
      merge_g<<<dim3(8, 16, 2), 256, 0, stream>>>(
          segs + S, segs, T10, 2 * S, 2 * S, S, 132, 132);
      merge_g<<<dim3(8, 16, 1), 256, 0, stream>>>(
          T32, T10, Tf, 0, 0, 0, 264, 264);
    } else if (nseg == 2) {
      Tf = base;
      merge_g<<<dim3(8, 16, 1), 256, 0, stream>>>(
          segs + S, segs, Tf, 0, 0, 0, 260, 260);
    } else {
      Tf = segs;
    }

    gemm_mfma<<<dim3(BATCH / 128, 8), 256, 0, stream>>>(Tf, x, (float*)d_out);
  }
}